// Round 7
// baseline (22157.347 us; speedup 1.0000x reference)
//
#include <hip/hip_runtime.h>
#include <stdint.h>

// ---------------------------------------------------------------------------
// KerasLMU — R7 structural rewrite.
//   m-recurrence (linear, h-independent) folded OUT of the serial chain:
//     m_t = A m_{t-1} + b u_t  ==> precomputed via chunked scan (L=64):
//       Apow[k-1]=A^k (doubling); V_k = A^k b; per-batch chunk recurrence
//       m_start[b,c] (64 independent blocks, no sync);
//       out += Dstack[i] @ m_start  (Dstack[i] = W_m A^{i+1})   [MFMA GEMM]
//       out += Toeplitz(u) M2 @ W_m^T                            [MFMA GEMM]
//     so out holds pre_t = xW_x + W_m m_t before the serial kernel.
//   Serial chain is h-only: h_t = LReLU(pre_t + W_h h_{t-1}), K=512.
//   k_seq: 4 groups x 16 batches, 4 WGs/group (16 blocks, 512 thr), wave-
//   autonomous: each wave owns 32 rows x K-half(256), weights in 32 NAMED
//   asm-loaded u32x4 frags (SROA-safe -> truly register-resident), one
//   pair-exchange barrier, per-wave finish+flag. Proven R3 sync protocol
//   (relaxed polls, manual release: vmcnt(0)+relaxed flag store).
// ---------------------------------------------------------------------------

typedef _Float16 half8 __attribute__((ext_vector_type(8)));
typedef float f32x4 __attribute__((ext_vector_type(4)));
typedef unsigned int u32x4 __attribute__((ext_vector_type(4)));

union H8 { half8 h; unsigned int u[4]; };

#define MFMA16(a, b, c) __builtin_amdgcn_mfma_f32_16x16x32_f16((a), (b), (c), 0, 0, 0)
#define ALOAD(p) __hip_atomic_load((p), __ATOMIC_RELAXED, __HIP_MEMORY_SCOPE_AGENT)
#define ASTORE(p, v) __hip_atomic_store((p), (v), __ATOMIC_RELAXED, __HIP_MEMORY_SCOPE_AGENT)

__device__ __forceinline__ half8 load_w_frag(const _Float16* W, size_t base) {
    H8 r;
    const unsigned int* p0 = (const unsigned int*)(W + base);
    const unsigned int* p1 = (const unsigned int*)(W + base + 16);
    r.u[0] = p0[0]; r.u[1] = p0[1];
    r.u[2] = p1[0]; r.u[3] = p1[1];
    return r.h;
}

__device__ __forceinline__ void unpack8(u32x4 A, u32x4 B, half8& hi, half8& lo) {
    H8 h, l;
    h.u[0] = (A[0] & 0xffffu) | (A[1] << 16);  l.u[0] = (A[0] >> 16) | (A[1] & 0xffff0000u);
    h.u[1] = (A[2] & 0xffffu) | (A[3] << 16);  l.u[1] = (A[2] >> 16) | (A[3] & 0xffff0000u);
    h.u[2] = (B[0] & 0xffffu) | (B[1] << 16);  l.u[2] = (B[0] >> 16) | (B[1] & 0xffff0000u);
    h.u[3] = (B[2] & 0xffffu) | (B[3] << 16);  l.u[3] = (B[2] >> 16) | (B[3] & 0xffff0000u);
    hi = h.h; lo = l.h;
}

// ---------------------------------------------------------------------------
// k_prep: W_h fp16 splits FRAGMENT-MAJOR (512x512):
//   idx(r,cb,kgi,e) = ((r*16+cb)*4+kgi)*8+e, cb=c>>5, kgi=((c&31)&15)>>2,
//   e=(c&3)+((c&16)?4:0).  WxT row-major (k_pre).  WmHi/Lo row-major [n][d].
//   AT = A^T fp32 (for k_vk coalesced reads).
// ---------------------------------------------------------------------------
__global__ void k_prep(const float* __restrict__ A, const float* __restrict__ W_x,
                       const float* __restrict__ W_h, const float* __restrict__ W_m,
                       _Float16* __restrict__ Whi, _Float16* __restrict__ Wlo,
                       _Float16* __restrict__ WxThi, _Float16* __restrict__ WxTlo,
                       _Float16* __restrict__ WmHi, _Float16* __restrict__ WmLo,
                       float* __restrict__ AT) {
    int bid = blockIdx.x, tid = threadIdx.x;
    if (bid < 512) {
        int r = bid;
        for (int c = tid; c < 512; c += 256) {
            float v = W_h[(size_t)r * 512 + c];
            _Float16 hi = (_Float16)v;
            _Float16 lo = (_Float16)(v - (float)hi);
            int cb = c >> 5, w = c & 31;
            int kgi = (w & 15) >> 2;
            int e = (w & 3) + ((w & 16) ? 4 : 0);
            size_t idx = (((size_t)r * 16 + cb) * 4 + kgi) * 8 + e;
            Whi[idx] = hi;
            Wlo[idx] = lo;
        }
    } else if (bid < 1024) {
        int n = bid - 512;
        if (tid < 128) {
            float v = W_x[(size_t)tid * 512 + n];
            _Float16 hi = (_Float16)v;
            _Float16 lo = (_Float16)(v - (float)hi);
            WxThi[(size_t)n * 128 + tid] = hi;
            WxTlo[(size_t)n * 128 + tid] = lo;
        }
    } else if (bid < 1536) {
        int n = bid - 1024;
        if (tid < 256) {
            float v = W_m[(size_t)n * 256 + tid];
            _Float16 hi = (_Float16)v;
            _Float16 lo = (_Float16)(v - (float)hi);
            WmHi[(size_t)n * 256 + tid] = hi;
            WmLo[(size_t)n * 256 + tid] = lo;
        }
    } else {
        int e = bid - 1536;
        if (tid < 256) AT[(size_t)e * 256 + tid] = A[(size_t)tid * 256 + e];
    }
}

// ---------------------------------------------------------------------------
__global__ void k_u(const float* __restrict__ x, const float* __restrict__ e_x,
                    float* __restrict__ u) {
    int wave = threadIdx.x >> 6, l = threadIdx.x & 63;
    int t = blockIdx.x * 4 + wave;
    int b = blockIdx.y;
    const float* xr = x + ((size_t)b * 1025 + t + 1) * 128;
    float s = xr[2 * l] * e_x[2 * l] + xr[2 * l + 1] * e_x[2 * l + 1];
#pragma unroll
    for (int off = 1; off < 64; off <<= 1) s += __shfl_xor(s, off);
    if (l == 0) u[(size_t)b * 1024 + t] = s;
}

// ---------------------------------------------------------------------------
// k_pre: out[b][s][n] = sum_f x[b][s+1][f] * W_x[f][n]  (proven kernel)
// ---------------------------------------------------------------------------
__global__ __launch_bounds__(256, 1) void k_pre(const float* __restrict__ x,
                                                const _Float16* __restrict__ WxThi,
                                                const _Float16* __restrict__ WxTlo,
                                                float* __restrict__ out) {
    __shared__ float xt[64][132];
    int tid = threadIdx.x;
    int Mb = blockIdx.x, Nb = blockIdx.y;
    int b = (Mb * 64) >> 10;
    int t0 = (Mb * 64) & 1023;
    const float* src = x + ((size_t)b * 1025 + t0 + 1) * 128;
#pragma unroll
    for (int i = 0; i < 8; ++i) {
        int idx = tid + i * 256;
        int row = idx >> 5, c4 = (idx & 31) * 4;
        *(f32x4*)&xt[row][c4] = *(const f32x4*)(src + (size_t)row * 128 + c4);
    }
    __syncthreads();

    int wave = tid >> 6, l = tid & 63;
    int kg = (l >> 4) * 4;
    int mrow = wave * 16 + (l & 15);

    half8 ah[4], al[4];
#pragma unroll
    for (int kt = 0; kt < 4; ++kt) {
        f32x4 f0 = *(const f32x4*)&xt[mrow][kt * 32 + kg];
        f32x4 f1 = *(const f32x4*)&xt[mrow][kt * 32 + kg + 16];
        H8 hh, ll;
#pragma unroll
        for (int e = 0; e < 4; ++e) {
            _Float16 h0 = (_Float16)f0[e];
            ((_Float16*)&hh)[e] = h0;
            ((_Float16*)&ll)[e] = (_Float16)(f0[e] - (float)h0);
            _Float16 h1 = (_Float16)f1[e];
            ((_Float16*)&hh)[e + 4] = h1;
            ((_Float16*)&ll)[e + 4] = (_Float16)(f1[e] - (float)h1);
        }
        ah[kt] = hh.h;
        al[kt] = ll.h;
    }

    f32x4 acc[16];
#pragma unroll
    for (int nt = 0; nt < 16; ++nt) acc[nt] = (f32x4)0.f;

#pragma unroll
    for (int nt = 0; nt < 16; ++nt) {
        size_t nrow = (size_t)(Nb * 256 + nt * 16 + (l & 15));
#pragma unroll
        for (int kt = 0; kt < 4; ++kt) {
            size_t base = nrow * 128 + kt * 32 + kg;
            half8 bh = load_w_frag(WxThi, base);
            half8 bl = load_w_frag(WxTlo, base);
            acc[nt] = MFMA16(ah[kt], bh, acc[nt]);
            acc[nt] = MFMA16(al[kt], bh, acc[nt]);
            acc[nt] = MFMA16(ah[kt], bl, acc[nt]);
        }
    }

#pragma unroll
    for (int nt = 0; nt < 16; ++nt) {
#pragma unroll
        for (int r = 0; r < 4; ++r) {
            size_t bt = (size_t)Mb * 64 + wave * 16 + 4 * (l >> 4) + r;
            out[bt * 512 + Nb * 256 + nt * 16 + (l & 15)] = acc[nt][r];
        }
    }
}

// ---------------------------------------------------------------------------
// k_apow: Apow[k-1] = A^k, k=1..64, fp32, by doubling.
//   stage 0 (grid 1): Apow[0] = A.
//   stage j>=1 (grid 2^{j-1}): block kk=bid+1: Apow[P+kk-1]=Apow[kk-1]@Apow[P-1].
// ---------------------------------------------------------------------------
__global__ void k_apow(const float* __restrict__ A, float* __restrict__ Apow,
                       int stage) {
    int tid = threadIdx.x;
    if (stage == 0) {
        for (int idx = tid; idx < 65536; idx += 1024) Apow[idx] = A[idx];
        return;
    }
    int P = 1 << (stage - 1);
    const float* L = Apow + (size_t)blockIdx.x * 65536;
    const float* R = Apow + (size_t)(P - 1) * 65536;
    float* O = Apow + (size_t)(P + blockIdx.x) * 65536;
    int d = tid >> 2, fc = (tid & 3) * 64;
    float acc[64];
#pragma unroll
    for (int f = 0; f < 64; ++f) acc[f] = 0.f;
    for (int e = 0; e < 256; ++e) {
        float a = L[(size_t)d * 256 + e];
        const float* Rr = R + (size_t)e * 256 + fc;
#pragma unroll
        for (int f = 0; f < 64; ++f) acc[f] += a * Rr[f];
    }
#pragma unroll
    for (int f = 0; f < 64; ++f) O[(size_t)d * 256 + fc + f] = acc[f];
}

// A64T[e][d] = A^64[d][e] (coalesced matvec in k_mstart)
__global__ void k_at64(const float* __restrict__ Apow, float* __restrict__ A64T) {
    int e = blockIdx.x, tid = threadIdx.x;
    A64T[(size_t)e * 256 + tid] = Apow[(size_t)63 * 65536 + (size_t)tid * 256 + e];
}

// ---------------------------------------------------------------------------
// k_vk: V[k][d] = (A^k b)[d], k=0..63.  Single block, AT-coalesced.
// ---------------------------------------------------------------------------
__global__ void k_vk(const float* __restrict__ AT, const float* __restrict__ Bv,
                     float* __restrict__ V) {
    __shared__ float cur[256];
    int tid = threadIdx.x;
    cur[tid] = Bv[tid];
    V[tid] = cur[tid];
    __syncthreads();
    for (int k = 1; k < 64; ++k) {
        float nv = 0.f;
        for (int e = 0; e < 256; ++e) nv += AT[(size_t)e * 256 + tid] * cur[e];
        __syncthreads();
        cur[tid] = nv;
        V[(size_t)k * 256 + tid] = nv;
        __syncthreads();
    }
}

// ---------------------------------------------------------------------------
// k_mstart: per-batch chunk recurrence (64 independent blocks, no sync):
//   ms[b,0]=0; ms[b,c+1] = A^64 ms[b,c] + sum_j V[63-j] u[b,64c+j].
//   Emits fp16 hi/lo split msHi/msLo[(b*16+c)*256+d].
// ---------------------------------------------------------------------------
__global__ void k_mstart(const float* __restrict__ A64T, const float* __restrict__ V,
                         const float* __restrict__ u,
                         _Float16* __restrict__ msHi, _Float16* __restrict__ msLo) {
    __shared__ float Vl[64 * 256];
    __shared__ float cur[256];
    __shared__ float ul[64];
    int b = blockIdx.x, tid = threadIdx.x;
    for (int idx = tid; idx < 64 * 256; idx += 256) Vl[idx] = V[idx];
    cur[tid] = 0.f;
    __syncthreads();
    for (int c = 0; c < 16; ++c) {
        float v = cur[tid];
        _Float16 hi = (_Float16)v;
        msHi[((size_t)b * 16 + c) * 256 + tid] = hi;
        msLo[((size_t)b * 16 + c) * 256 + tid] = (_Float16)(v - (float)hi);
        if (tid < 64) ul[tid] = u[(size_t)b * 1024 + c * 64 + tid];
        __syncthreads();
        float nm = 0.f;
        for (int j = 0; j < 64; ++j) nm += Vl[(63 - j) * 256 + tid] * ul[j];
        for (int e = 0; e < 256; ++e) nm += A64T[(size_t)e * 256 + tid] * cur[e];
        __syncthreads();
        cur[tid] = nm;
        __syncthreads();
    }
}

// ---------------------------------------------------------------------------
// k_dstack: Dst[i][n][d] = (W_m @ A^{i+1})[n][d], fp16 hi/lo.  64 blocks x 1024.
// ---------------------------------------------------------------------------
__global__ void k_dstack(const float* __restrict__ Apow, const float* __restrict__ W_m,
                         _Float16* __restrict__ DstHi, _Float16* __restrict__ DstLo) {
    int i = blockIdx.x, tid = threadIdx.x;
    int n = tid >> 1, dh = tid & 1;
    for (int ch = 0; ch < 2; ++ch) {
        int d0 = dh * 128 + ch * 64;
        float acc[64];
#pragma unroll
        for (int f = 0; f < 64; ++f) acc[f] = 0.f;
        for (int e = 0; e < 256; ++e) {
            float wv = W_m[(size_t)n * 256 + e];
            const float* Ar = Apow + (size_t)i * 65536 + (size_t)e * 256 + d0;
#pragma unroll
            for (int f = 0; f < 64; ++f) acc[f] += wv * Ar[f];
        }
#pragma unroll
        for (int f = 0; f < 64; ++f) {
            float v = acc[f];
            _Float16 hi = (_Float16)v;
            size_t idx = ((size_t)i * 512 + n) * 256 + d0 + f;
            DstHi[idx] = hi;
            DstLo[idx] = (_Float16)(v - (float)hi);
        }
    }
}

// ---------------------------------------------------------------------------
// k_pt1m: out[b, 64c+i, n] += Dst[i] @ ms[b,c]   (MFMA, k_pre pattern, K=256)
// grid (16 Mb over bc, 2 Nb, 64 i), 256 thr.
// ---------------------------------------------------------------------------
__global__ __launch_bounds__(256, 1) void k_pt1m(const _Float16* __restrict__ msHi,
                                                 const _Float16* __restrict__ msLo,
                                                 const _Float16* __restrict__ DstHi,
                                                 const _Float16* __restrict__ DstLo,
                                                 float* __restrict__ out) {
    int tid = threadIdx.x;
    int Mb = blockIdx.x, Nb = blockIdx.y, i = blockIdx.z;
    int wave = tid >> 6, l = tid & 63;
    int kg = (l >> 4) * 4;
    int arow = Mb * 64 + wave * 16 + (l & 15);

    half8 ah[8], al[8];
#pragma unroll
    for (int kt = 0; kt < 8; ++kt) {
        size_t base = (size_t)arow * 256 + kt * 32 + kg;
        ah[kt] = load_w_frag(msHi, base);
        al[kt] = load_w_frag(msLo, base);
    }

    f32x4 acc[16];
#pragma unroll
    for (int nt = 0; nt < 16; ++nt) acc[nt] = (f32x4)0.f;

#pragma unroll
    for (int nt = 0; nt < 16; ++nt) {
        size_t nrow = (size_t)i * 512 + Nb * 256 + nt * 16 + (l & 15);
#pragma unroll
        for (int kt = 0; kt < 8; ++kt) {
            size_t base = nrow * 256 + kt * 32 + kg;
            half8 bh = load_w_frag(DstHi, base);
            half8 bl = load_w_frag(DstLo, base);
            acc[nt] = MFMA16(ah[kt], bh, acc[nt]);
            acc[nt] = MFMA16(al[kt], bh, acc[nt]);
            acc[nt] = MFMA16(ah[kt], bl, acc[nt]);
        }
    }

#pragma unroll
    for (int nt = 0; nt < 16; ++nt) {
#pragma unroll
        for (int r = 0; r < 4; ++r) {
            int bcrow = Mb * 64 + wave * 16 + 4 * (l >> 4) + r;
            int b = bcrow >> 4, c = bcrow & 15;
            size_t addr = ((size_t)b * 1024 + c * 64 + i) * 512 + Nb * 256 + nt * 16 + (l & 15);
            out[addr] += acc[nt][r];
        }
    }
}

// ---------------------------------------------------------------------------
// k_m2p: per (b,c): M2[i][d] = sum_{j<=i} V[i-j][d] u[b,64c+j]  (VALU Toeplitz)
//        out[b, 64c+i, :] += M2 @ W_m^T                          (MFMA, K=256)
// grid 1024 (bc), 256 thr; Nb-loop inside.
// ---------------------------------------------------------------------------
__global__ __launch_bounds__(256, 1) void k_m2p(const float* __restrict__ V,
                                                const _Float16* __restrict__ WmHi,
                                                const _Float16* __restrict__ WmLo,
                                                const float* __restrict__ u,
                                                float* __restrict__ out) {
    __shared__ float ul[64];
    __shared__ float M2[64][260];
    int tid = threadIdx.x;
    int bc = blockIdx.x, b = bc >> 4, c = bc & 15;
    if (tid < 64) ul[tid] = u[(size_t)b * 1024 + c * 64 + tid];
    __syncthreads();
    for (int i = 0; i < 64; ++i) {
        float a = 0.f;
        for (int j = 0; j <= i; ++j) a += V[(size_t)(i - j) * 256 + tid] * ul[j];
        M2[i][tid] = a;
    }
    __syncthreads();

    int wave = tid >> 6, l = tid & 63;
    int kg = (l >> 4) * 4;
    int mrow = wave * 16 + (l & 15);

    half8 ah[8], al[8];
#pragma unroll
    for (int kt = 0; kt < 8; ++kt) {
        f32x4 f0 = *(const f32x4*)&M2[mrow][kt * 32 + kg];
        f32x4 f1 = *(const f32x4*)&M2[mrow][kt * 32 + kg + 16];
        H8 hh, ll;
#pragma unroll
        for (int e = 0; e < 4; ++e) {
            _Float16 h0 = (_Float16)f0[e];
            ((_Float16*)&hh)[e] = h0;
            ((_Float16*)&ll)[e] = (_Float16)(f0[e] - (float)h0);
            _Float16 h1 = (_Float16)f1[e];
            ((_Float16*)&hh)[e + 4] = h1;
            ((_Float16*)&ll)[e + 4] = (_Float16)(f1[e] - (float)h1);
        }
        ah[kt] = hh.h;
        al[kt] = ll.h;
    }

    for (int Nb = 0; Nb < 2; ++Nb) {
        f32x4 acc[16];
#pragma unroll
        for (int nt = 0; nt < 16; ++nt) acc[nt] = (f32x4)0.f;
#pragma unroll
        for (int nt = 0; nt < 16; ++nt) {
            size_t nrow = (size_t)(Nb * 256 + nt * 16 + (l & 15));
#pragma unroll
            for (int kt = 0; kt < 8; ++kt) {
                size_t base = nrow * 256 + kt * 32 + kg;
                half8 bh = load_w_frag(WmHi, base);
                half8 bl = load_w_frag(WmLo, base);
                acc[nt] = MFMA16(ah[kt], bh, acc[nt]);
                acc[nt] = MFMA16(al[kt], bh, acc[nt]);
                acc[nt] = MFMA16(ah[kt], bl, acc[nt]);
            }
        }
#pragma unroll
        for (int nt = 0; nt < 16; ++nt) {
#pragma unroll
            for (int r = 0; r < 4; ++r) {
                int irow = wave * 16 + 4 * (l >> 4) + r;
                size_t addr = ((size_t)b * 1024 + c * 64 + irow) * 512 + Nb * 256 + nt * 16 + (l & 15);
                out[addr] += acc[nt][r];
            }
        }
    }
}

// ---------------------------------------------------------------------------
// k_seq: h-only serial chain. 16 blocks x 512 thr, wave-autonomous.
// Wave w of WG rank r: rows rank*128 + (w&3)*32 + {0..31}, K-half kh=w>>2.
// Weights: 32 NAMED u32x4 (asm loads, SROA-safe -> register-resident).
// One barrier/step (pair partial exchange). Flags: 32/group, monotone step.
// ---------------------------------------------------------------------------
#define STATE_U32 (64 * 512)

#define LD8W(p, v0, v1, v2, v3, v4, v5, v6, v7)                                   \
    asm volatile("global_load_dwordx4 %0, %8, off\n\t"                            \
                 "global_load_dwordx4 %1, %8, off offset:64\n\t"                  \
                 "global_load_dwordx4 %2, %8, off offset:128\n\t"                 \
                 "global_load_dwordx4 %3, %8, off offset:192\n\t"                 \
                 "global_load_dwordx4 %4, %8, off offset:256\n\t"                 \
                 "global_load_dwordx4 %5, %8, off offset:320\n\t"                 \
                 "global_load_dwordx4 %6, %8, off offset:384\n\t"                 \
                 "global_load_dwordx4 %7, %8, off offset:448"                     \
                 : "=&v"(v0), "=&v"(v1), "=&v"(v2), "=&v"(v3), "=&v"(v4),         \
                   "=&v"(v5), "=&v"(v6), "=&v"(v7)                                \
                 : "v"(p))

#define BC8(x) __builtin_bit_cast(half8, x)

#define KSTEP(QA, QB, BH0, BL0, BH1, BL1)                                         \
    {                                                                             \
        half8 Ah, Al;                                                             \
        unpack8(QA, QB, Ah, Al);                                                  \
        acc0 = MFMA16(Ah, BC8(BH0), acc0);                                        \
        acc0 = MFMA16(Al, BC8(BH0), acc0);                                        \
        acc0 = MFMA16(Ah, BC8(BL0), acc0);                                        \
        acc1 = MFMA16(Ah, BC8(BH1), acc1);                                        \
        acc1 = MFMA16(Al, BC8(BH1), acc1);                                        \
        acc1 = MFMA16(Ah, BC8(BL1), acc1);                                        \
    }

__global__ __launch_bounds__(512, 2) void k_seq(const _Float16* __restrict__ Whi,
                                                const _Float16* __restrict__ Wlo,
                                                unsigned int* sbuf, int* flags,
                                                float* out) {
    __shared__ f32x4 pex[8][64];
    int tid = threadIdx.x;
    int w = tid >> 6, l = tid & 63;
    int g = blockIdx.x >> 2, rank = blockIdx.x & 3;
    int kh = w >> 2;              // K-half
    int kbase = kh * 256;
    int kg4 = l >> 4, kg = kg4 * 4;
    int rowBase = rank * 128;

    // ---- weight preload: 32 named frags via asm (register-resident) ----
    u32x4 h0_0, h0_1, h0_2, h0_3, h0_4, h0_5, h0_6, h0_7;
    u32x4 h1_0, h1_1, h1_2, h1_3, h1_4, h1_5, h1_6, h1_7;
    u32x4 l0_0, l0_1, l0_2, l0_3, l0_4, l0_5, l0_6, l0_7;
    u32x4 l1_0, l1_1, l1_2, l1_3, l1_4, l1_5, l1_6, l1_7;
    {
        int rowA = rowBase + (w & 3) * 32 + (l & 15);
        int rowB = rowA + 16;
        int cb0 = kh * 8;
        size_t foA = (((size_t)rowA * 16 + cb0) * 4 + kg4) * 8;
        size_t foB = (((size_t)rowB * 16 + cb0) * 4 + kg4) * 8;
        LD8W(Whi + foA, h0_0, h0_1, h0_2, h0_3, h0_4, h0_5, h0_6, h0_7);
        LD8W(Whi + foB, h1_0, h1_1, h1_2, h1_3, h1_4, h1_5, h1_6, h1_7);
        LD8W(Wlo + foA, l0_0, l0_1, l0_2, l0_3, l0_4, l0_5, l0_6, l0_7);
        LD8W(Wlo + foB, l1_0, l1_1, l1_2, l1_3, l1_4, l1_5, l1_6, l1_7);
        asm volatile("s_waitcnt vmcnt(0)" ::: "memory");
    }

    int frow = rowBase + (w & 3) * 32 + kh * 16 + (l & 15);  // rows this wave finishes
    int bA = g * 16 + (l & 15);
    int* gflags = flags + g * 64;

#pragma unroll 1
    for (int t = 1; t <= 1024; ++t) {
        // ---- prefetch pre-values (own lanes only; safe any time) ----
        float pxw[4];
#pragma unroll
        for (int r = 0; r < 4; ++r) {
            int bG = g * 16 + 4 * (l >> 4) + r;
            pxw[r] = out[(((size_t)bG << 10) + (t - 1)) * 512 + frow];
        }

        // ---- every wave polls all 32 flags (relaxed) ----
        for (;;) {
            int a = 0x7fffffff;
            if (l < 32) a = ALOAD(&gflags[l]);
            if (__all(a >= t - 1)) break;
            __builtin_amdgcn_s_sleep(1);
        }

        // ---- state loads: 16 dwordx4, one base, one wait ----
        const unsigned int* rb = sbuf + (size_t)((t - 1) & 1) * STATE_U32;
        const unsigned int* pS = rb + (size_t)bA * 512 + kbase + kg;
        u32x4 q0, q1, q2, q3, q4, q5, q6, q7, q8, q9, q10, q11, q12, q13, q14, q15;
        asm volatile(
            "global_load_dwordx4 %0, %16, off sc1\n\t"
            "global_load_dwordx4 %1, %16, off offset:64 sc1\n\t"
            "global_load_dwordx4 %2, %16, off offset:128 sc1\n\t"
            "global_load_dwordx4 %3, %16, off offset:192 sc1\n\t"
            "global_load_dwordx4 %4, %16, off offset:256 sc1\n\t"
            "global_load_dwordx4 %5, %16, off offset:320 sc1\n\t"
            "global_load_dwordx4 %6, %16, off offset:384 sc1\n\t"
            "global_load_dwordx4 %7, %16, off offset:448 sc1\n\t"
            "global_load_dwordx4 %8, %16, off offset:512 sc1\n\t"
            "global_load_dwordx4 %9, %16, off offset:576 sc1\n\t"
            "global_load_dwordx4 %10, %16, off offset:640 sc1\n\t"
            "global_load_dwordx4 %11, %16, off offset:704 sc1\n\t"
            "global_load_dwordx4 %12, %16, off offset:768 sc1\n\t"
            "global_load_dwordx4 %13, %16, off offset:832 sc1\n\t"
            "global_load_dwordx4 %14, %16, off offset:896 sc1\n\t"
            "global_load_dwordx4 %15, %16, off offset:960 sc1\n\t"
            "s_waitcnt vmcnt(0)"
            : "=&v"(q0), "=&v"(q1), "=&v"(q2), "=&v"(q3), "=&v"(q4), "=&v"(q5),
              "=&v"(q6), "=&v"(q7), "=&v"(q8), "=&v"(q9), "=&v"(q10), "=&v"(q11),
              "=&v"(q12), "=&v"(q13), "=&v"(q14), "=&v"(q15)
            : "v"(pS) : "memory");

        // ---- 48 MFMAs: acc0 = rows +0..15, acc1 = rows +16..31 ----
        f32x4 acc0 = (f32x4)0.f, acc1 = (f32x4)0.f;
        KSTEP(q0, q1, h0_0, l0_0, h1_0, l1_0);
        KSTEP(q2, q3, h0_1, l0_1, h1_1, l1_1);
        KSTEP(q4, q5, h0_2, l0_2, h1_2, l1_2);
        KSTEP(q6, q7, h0_3, l0_3, h1_3, l1_3);
        KSTEP(q8, q9, h0_4, l0_4, h1_4, l1_4);
        KSTEP(q10, q11, h0_5, l0_5, h1_5, l1_5);
        KSTEP(q12, q13, h0_6, l0_6, h1_6, l1_6);
        KSTEP(q14, q15, h0_7, l0_7, h1_7, l1_7);

        // ---- pair exchange: publish the partial my partner finishes ----
        pex[w][l] = kh ? acc0 : acc1;
        __syncthreads();
        f32x4 sum = (kh ? acc1 : acc0) + pex[w ^ 4][l];
        // (pex reuse safe: my next write happens only after my poll sees
        //  partner's flag >= t, which is set after partner's read.)

        // ---- finish: leakyrelu, store state, drain, flag, out ----
        unsigned int* wb = sbuf + (size_t)(t & 1) * STATE_U32;
        float vout[4];
#pragma unroll
        for (int r = 0; r < 4; ++r) {
            int bG = g * 16 + 4 * (l >> 4) + r;
            float v = sum[r] + pxw[r];
            v = (v >= 0.f) ? v : 0.2f * v;
            vout[r] = v;
            _Float16 hi = (_Float16)v;
            _Float16 lo = (_Float16)(v - (float)hi);
            unsigned int pr = (unsigned int)__builtin_bit_cast(unsigned short, hi) |
                              ((unsigned int)__builtin_bit_cast(unsigned short, lo) << 16);
            ASTORE(wb + (size_t)bG * 512 + frow, pr);
        }
        asm volatile("s_waitcnt vmcnt(0)" ::: "memory");  // manual release
        ASTORE(&gflags[rank * 8 + w], t);
#pragma unroll
        for (int r = 0; r < 4; ++r) {
            int bG = g * 16 + 4 * (l >> 4) + r;
            out[(((size_t)bG << 10) + (t - 1)) * 512 + frow] = vout[r];
        }
    }
}

// ---------------------------------------------------------------------------
extern "C" void kernel_launch(void* const* d_in, const int* in_sizes, int n_in,
                              void* d_out, int out_size, void* d_ws, size_t ws_size,
                              hipStream_t stream) {
    const float* x   = (const float*)d_in[0];
    const float* A   = (const float*)d_in[1];
    const float* Bv  = (const float*)d_in[2];
    const float* W_x = (const float*)d_in[3];
    const float* e_x = (const float*)d_in[4];
    const float* W_h = (const float*)d_in[5];
    const float* W_m = (const float*)d_in[6];
    float* out = (float*)d_out;

    char* ws = (char*)d_ws;
    size_t off = 0;
    auto carve = [&](size_t n) -> char* {
        char* p = ws + off;
        off += (n + 255) & ~(size_t)255;
        return p;
    };
    _Float16* Whi   = (_Float16*)carve(512 * 512 * 2);
    _Float16* Wlo   = (_Float16*)carve(512 * 512 * 2);
    _Float16* WxThi = (_Float16*)carve(512 * 128 * 2);
    _Float16* WxTlo = (_Float16*)carve(512 * 128 * 2);
    _Float16* WmHi  = (_Float16*)carve(512 * 256 * 2);
    _Float16* WmLo  = (_Float16*)carve(512 * 256 * 2);
    float* AT       = (float*)carve(256 * 256 * 4);
    float* u        = (float*)carve(64 * 1024 * 4);
    unsigned int* sbuf = (unsigned int*)carve(2 * STATE_U32 * 4);
    int* flags      = (int*)carve(4 * 64 * 4);
    float* V        = (float*)carve(64 * 256 * 4);
    float* A64T     = (float*)carve(256 * 256 * 4);
    float* Apow     = (float*)carve((size_t)64 * 65536 * 4);
    _Float16* msHi  = (_Float16*)carve(1024 * 256 * 2);
    _Float16* msLo  = (_Float16*)carve(1024 * 256 * 2);
    _Float16* DstHi = (_Float16*)carve((size_t)64 * 512 * 256 * 2);
    _Float16* DstLo = (_Float16*)carve((size_t)64 * 512 * 256 * 2);

    // zero state ping-pong + flags (adjacent carves)
    hipMemsetAsync(sbuf, 0, (size_t)2 * STATE_U32 * 4 + 4 * 64 * 4, stream);

    hipLaunchKernelGGL(k_prep, dim3(1792), dim3(256), 0, stream, A, W_x, W_h, W_m,
                       Whi, Wlo, WxThi, WxTlo, WmHi, WmLo, AT);
    hipLaunchKernelGGL(k_u, dim3(256, 64), dim3(256), 0, stream, x, e_x, u);
    hipLaunchKernelGGL(k_pre, dim3(1024, 2), dim3(256), 0, stream, x, WxThi, WxTlo, out);

    hipLaunchKernelGGL(k_apow, dim3(1), dim3(1024), 0, stream, A, Apow, 0);
    for (int s = 1; s <= 6; ++s)
        hipLaunchKernelGGL(k_apow, dim3(1 << (s - 1)), dim3(1024), 0, stream, A, Apow, s);
    hipLaunchKernelGGL(k_at64, dim3(256), dim3(256), 0, stream, Apow, A64T);
    hipLaunchKernelGGL(k_vk, dim3(1), dim3(256), 0, stream, AT, Bv, V);
    hipLaunchKernelGGL(k_mstart, dim3(64), dim3(256), 0, stream, A64T, V, u, msHi, msLo);
    hipLaunchKernelGGL(k_dstack, dim3(64), dim3(1024), 0, stream, Apow, W_m, DstHi, DstLo);
    hipLaunchKernelGGL(k_pt1m, dim3(16, 2, 64), dim3(256), 0, stream, msHi, msLo,
                       DstHi, DstLo, out);
    hipLaunchKernelGGL(k_m2p, dim3(1024), dim3(256), 0, stream, V, WmHi, WmLo, u, out);

    void* args[] = {(void*)&Whi, (void*)&Wlo, (void*)&sbuf, (void*)&flags, (void*)&out};
    hipLaunchCooperativeKernel((void*)k_seq, dim3(16), dim3(512), args, 0, stream);
}

// Round 8
// 7351.530 us; speedup vs baseline: 3.0140x; 3.0140x over previous
//
#include <hip/hip_runtime.h>
#include <stdint.h>

// ---------------------------------------------------------------------------
// KerasLMU — R8.
// m-path as causal convolution (no serial m in the chain):
//   W_m m_tau = sum_k c_k u[tau-k],  c_k = W_m A^k b.
//   V_k = A^k b: k_vk (64 serial matvecs) + A^64 (6 squarings) + 15 chunk
//   launches V_{k+64} = A^64 V_k.  c = W_m @ V (k_c).  Conv fused into the
//   pre-GEMM (k_preconv): out = x@W_x (fp16 3-split) + Toeplitz(u)@c (fp16
//   single, err ~1e-3 << 0.133).  No += RMW passes.
// Serial chain h-only: h_t = LReLU(pre_t + W_h h_{t-1}), K=512.
// k_seq: 4 groups x 16 batches, 4 blocks/group x 8 waves. R7-verbatim compute
// (proven absmax 0.0156) + repaired sync: single-wave poll (R3 lesson) and
// ONE flag per block (fan-in 32->4, one cacheline): per-wave vmcnt(0) drain ->
// barrier -> tid0 flag store.
// ---------------------------------------------------------------------------

typedef _Float16 half8 __attribute__((ext_vector_type(8)));
typedef float f32x4 __attribute__((ext_vector_type(4)));
typedef unsigned int u32x4 __attribute__((ext_vector_type(4)));

union H8 { half8 h; unsigned int u[4]; };

#define MFMA16(a, b, c) __builtin_amdgcn_mfma_f32_16x16x32_f16((a), (b), (c), 0, 0, 0)
#define ALOAD(p) __hip_atomic_load((p), __ATOMIC_RELAXED, __HIP_MEMORY_SCOPE_AGENT)
#define ASTORE(p, v) __hip_atomic_store((p), (v), __ATOMIC_RELAXED, __HIP_MEMORY_SCOPE_AGENT)

__device__ __forceinline__ half8 load_w_frag(const _Float16* W, size_t base) {
    H8 r;
    const unsigned int* p0 = (const unsigned int*)(W + base);
    const unsigned int* p1 = (const unsigned int*)(W + base + 16);
    r.u[0] = p0[0]; r.u[1] = p0[1];
    r.u[2] = p1[0]; r.u[3] = p1[1];
    return r.h;
}

__device__ __forceinline__ void unpack8(u32x4 A, u32x4 B, half8& hi, half8& lo) {
    H8 h, l;
    h.u[0] = (A[0] & 0xffffu) | (A[1] << 16);  l.u[0] = (A[0] >> 16) | (A[1] & 0xffff0000u);
    h.u[1] = (A[2] & 0xffffu) | (A[3] << 16);  l.u[1] = (A[2] >> 16) | (A[3] & 0xffff0000u);
    h.u[2] = (B[0] & 0xffffu) | (B[1] << 16);  l.u[2] = (B[0] >> 16) | (B[1] & 0xffff0000u);
    h.u[3] = (B[2] & 0xffffu) | (B[3] << 16);  l.u[3] = (B[2] >> 16) | (B[3] & 0xffff0000u);
    hi = h.h; lo = l.h;
}

// ---------------------------------------------------------------------------
// k_prep: W_h fp16 splits FRAGMENT-MAJOR (512x512, 16 col-blocks):
//   idx(r,cb,kgi,e) = ((r*16+cb)*4+kgi)*8+e.  WxT row-major.  WmT = W_m^T fp32.
//   AT = A^T fp32.
// ---------------------------------------------------------------------------
__global__ void k_prep(const float* __restrict__ A, const float* __restrict__ W_x,
                       const float* __restrict__ W_h, const float* __restrict__ W_m,
                       _Float16* __restrict__ Whi, _Float16* __restrict__ Wlo,
                       _Float16* __restrict__ WxThi, _Float16* __restrict__ WxTlo,
                       float* __restrict__ WmT, float* __restrict__ AT) {
    int bid = blockIdx.x, tid = threadIdx.x;
    if (bid < 512) {
        int r = bid;
        for (int c = tid; c < 512; c += 256) {
            float v = W_h[(size_t)r * 512 + c];
            _Float16 hi = (_Float16)v;
            _Float16 lo = (_Float16)(v - (float)hi);
            int cb = c >> 5, w = c & 31;
            int kgi = (w & 15) >> 2;
            int e = (w & 3) + ((w & 16) ? 4 : 0);
            size_t idx = (((size_t)r * 16 + cb) * 4 + kgi) * 8 + e;
            Whi[idx] = hi;
            Wlo[idx] = lo;
        }
    } else if (bid < 1024) {
        int n = bid - 512;
        if (tid < 128) {
            float v = W_x[(size_t)tid * 512 + n];
            _Float16 hi = (_Float16)v;
            _Float16 lo = (_Float16)(v - (float)hi);
            WxThi[(size_t)n * 128 + tid] = hi;
            WxTlo[(size_t)n * 128 + tid] = lo;
        }
    } else if (bid < 1280) {
        int d = bid - 1024;
        for (int n = tid; n < 512; n += 256)
            WmT[(size_t)d * 512 + n] = W_m[(size_t)n * 256 + d];
    } else {
        int e = bid - 1280;
        if (tid < 256) AT[(size_t)e * 256 + tid] = A[(size_t)tid * 256 + e];
    }
}

// ---------------------------------------------------------------------------
__global__ void k_u(const float* __restrict__ x, const float* __restrict__ e_x,
                    float* __restrict__ u) {
    int wave = threadIdx.x >> 6, l = threadIdx.x & 63;
    int t = blockIdx.x * 4 + wave;
    int b = blockIdx.y;
    const float* xr = x + ((size_t)b * 1025 + t + 1) * 128;
    float s = xr[2 * l] * e_x[2 * l] + xr[2 * l + 1] * e_x[2 * l + 1];
#pragma unroll
    for (int off = 1; off < 64; off <<= 1) s += __shfl_xor(s, off);
    if (l == 0) u[(size_t)b * 1024 + t] = s;
}

// ---------------------------------------------------------------------------
// k_a64: D = S @ S (one squaring). writeT: also D^T into DT (for matvecs).
// ---------------------------------------------------------------------------
__global__ void k_a64(const float* __restrict__ S, float* __restrict__ D,
                      float* __restrict__ DT, int writeT) {
    int r = blockIdx.x, c = threadIdx.x;
    float acc = 0.f;
    for (int e = 0; e < 256; ++e)
        acc += S[(size_t)r * 256 + e] * S[(size_t)e * 256 + c];
    D[(size_t)r * 256 + c] = acc;
    if (writeT) DT[(size_t)c * 256 + r] = acc;
}

// ---------------------------------------------------------------------------
// k_vk: V[k] = A^k b, k=0..63 (serial matvec chain, single block, AT-coalesced)
// ---------------------------------------------------------------------------
__global__ void k_vk(const float* __restrict__ AT, const float* __restrict__ Bv,
                     float* __restrict__ V) {
    __shared__ float cur[256];
    int tid = threadIdx.x;
    cur[tid] = Bv[tid];
    V[tid] = cur[tid];
    __syncthreads();
    for (int k = 1; k < 64; ++k) {
        float nv = 0.f;
        for (int e = 0; e < 256; ++e) nv += AT[(size_t)e * 256 + tid] * cur[e];
        __syncthreads();
        cur[tid] = nv;
        V[(size_t)k * 256 + tid] = nv;
        __syncthreads();
    }
}

// ---------------------------------------------------------------------------
// k_vchunk: V[(c+1)*64 + j] = A^64 @ V[c*64 + j]   (64 independent j-blocks)
// ---------------------------------------------------------------------------
__global__ void k_vchunk(const float* __restrict__ A64T, float* __restrict__ V,
                         int c) {
    int j = blockIdx.x, d = threadIdx.x;
    const float* vin = V + ((size_t)c * 64 + j) * 256;
    float acc = 0.f;
    for (int e = 0; e < 256; ++e) acc += A64T[(size_t)e * 256 + d] * vin[e];
    V[(((size_t)c + 1) * 64 + j) * 256 + d] = acc;
}

// ---------------------------------------------------------------------------
// k_c: CThi[n][k] = fp16( sum_d V[k][d] * W_m[n][d] )   (row-major [n][1024])
// ---------------------------------------------------------------------------
__global__ void k_c(const float* __restrict__ V, const float* __restrict__ WmT,
                    _Float16* __restrict__ CThi) {
    int k = blockIdx.x, n = threadIdx.x;
    const float* vk = V + (size_t)k * 256;
    float acc = 0.f;
    for (int d = 0; d < 256; ++d) acc += vk[d] * WmT[(size_t)d * 512 + n];
    CThi[(size_t)n * 1024 + k] = (_Float16)acc;
}

// ---------------------------------------------------------------------------
// k_preconv: out[b,tau,n] = x[b,tau+1]@W_x  (fp16 3-split, K=128)
//                          + sum_k u[b,tau-k] * c_k[n]  (fp16 single, K=1024)
// grid (1024, 2), 256 thr. Toeplitz A-frags built on the fly from LDS u.
// ---------------------------------------------------------------------------
__global__ __launch_bounds__(256, 1) void k_preconv(const float* __restrict__ x,
                                                    const float* __restrict__ u,
                                                    const _Float16* __restrict__ WxThi,
                                                    const _Float16* __restrict__ WxTlo,
                                                    const _Float16* __restrict__ CThi,
                                                    float* __restrict__ out) {
    __shared__ float xt[64][132];
    __shared__ float ut[1088];
    int tid = threadIdx.x;
    int Mb = blockIdx.x, Nb = blockIdx.y;
    int b = Mb >> 4;
    int t0 = (Mb & 15) * 64;
    const float* src = x + ((size_t)b * 1025 + t0 + 1) * 128;
#pragma unroll
    for (int i = 0; i < 8; ++i) {
        int idx = tid + i * 256;
        int row = idx >> 5, c4 = (idx & 31) * 4;
        *(f32x4*)&xt[row][c4] = *(const f32x4*)(src + (size_t)row * 128 + c4);
    }
    for (int i = tid; i < 1088; i += 256) {
        int tau = t0 - 1024 + i;
        ut[i] = (tau >= 0) ? u[(size_t)b * 1024 + tau] : 0.f;
    }
    __syncthreads();

    int wave = tid >> 6, l = tid & 63;
    int kg = (l >> 4) * 4;
    int mrow = wave * 16 + (l & 15);

    half8 ah[4], al[4];
#pragma unroll
    for (int kt = 0; kt < 4; ++kt) {
        f32x4 f0 = *(const f32x4*)&xt[mrow][kt * 32 + kg];
        f32x4 f1 = *(const f32x4*)&xt[mrow][kt * 32 + kg + 16];
        H8 hh, ll;
#pragma unroll
        for (int e = 0; e < 4; ++e) {
            _Float16 h0 = (_Float16)f0[e];
            ((_Float16*)&hh)[e] = h0;
            ((_Float16*)&ll)[e] = (_Float16)(f0[e] - (float)h0);
            _Float16 h1 = (_Float16)f1[e];
            ((_Float16*)&hh)[e + 4] = h1;
            ((_Float16*)&ll)[e + 4] = (_Float16)(f1[e] - (float)h1);
        }
        ah[kt] = hh.h;
        al[kt] = ll.h;
    }

    f32x4 acc[16];
#pragma unroll
    for (int nt = 0; nt < 16; ++nt) acc[nt] = (f32x4)0.f;

    // ---- x @ W_x (3-term split) ----
#pragma unroll
    for (int nt = 0; nt < 16; ++nt) {
        size_t nrow = (size_t)(Nb * 256 + nt * 16 + (l & 15));
#pragma unroll
        for (int kt = 0; kt < 4; ++kt) {
            size_t base = nrow * 128 + kt * 32 + kg;
            half8 bh = load_w_frag(WxThi, base);
            half8 bl = load_w_frag(WxTlo, base);
            acc[nt] = MFMA16(ah[kt], bh, acc[nt]);
            acc[nt] = MFMA16(al[kt], bh, acc[nt]);
            acc[nt] = MFMA16(ah[kt], bl, acc[nt]);
        }
    }

    // ---- Toeplitz(u) @ c  (single fp16, K=1024) ----
    for (int ck = 0; ck < 32; ++ck) {
        int base0 = mrow + 1024 - ck * 32 - kg;
        H8 au;
#pragma unroll
        for (int e = 0; e < 4; ++e) {
            ((_Float16*)&au)[e] = (_Float16)ut[base0 - e];
            ((_Float16*)&au)[e + 4] = (_Float16)ut[base0 - 16 - e];
        }
#pragma unroll
        for (int nt = 0; nt < 16; ++nt) {
            size_t nrow = (size_t)(Nb * 256 + nt * 16 + (l & 15));
            half8 bh = load_w_frag(CThi, nrow * 1024 + ck * 32 + kg);
            acc[nt] = MFMA16(au.h, bh, acc[nt]);
        }
    }

#pragma unroll
    for (int nt = 0; nt < 16; ++nt) {
#pragma unroll
        for (int r = 0; r < 4; ++r) {
            size_t bt = (size_t)Mb * 64 + wave * 16 + 4 * (l >> 4) + r;
            out[bt * 512 + Nb * 256 + nt * 16 + (l & 15)] = acc[nt][r];
        }
    }
}

// ---------------------------------------------------------------------------
// k_seq: h-only serial chain. 16 blocks (4 groups x 4 ranks) x 512 thr.
// Wave w: rows rank*128 + (w&3)*32, K-half kh=w>>2. One flag per BLOCK.
// ---------------------------------------------------------------------------
#define STATE_U32 (64 * 512)

#define LD8W(p, v0, v1, v2, v3, v4, v5, v6, v7)                                   \
    asm volatile("global_load_dwordx4 %0, %8, off\n\t"                            \
                 "global_load_dwordx4 %1, %8, off offset:64\n\t"                  \
                 "global_load_dwordx4 %2, %8, off offset:128\n\t"                 \
                 "global_load_dwordx4 %3, %8, off offset:192\n\t"                 \
                 "global_load_dwordx4 %4, %8, off offset:256\n\t"                 \
                 "global_load_dwordx4 %5, %8, off offset:320\n\t"                 \
                 "global_load_dwordx4 %6, %8, off offset:384\n\t"                 \
                 "global_load_dwordx4 %7, %8, off offset:448"                     \
                 : "=&v"(v0), "=&v"(v1), "=&v"(v2), "=&v"(v3), "=&v"(v4),         \
                   "=&v"(v5), "=&v"(v6), "=&v"(v7)                                \
                 : "v"(p))

#define BC8(x) __builtin_bit_cast(half8, x)

#define KSTEP(QA, QB, BH0, BL0, BH1, BL1)                                         \
    {                                                                             \
        half8 Ah, Al;                                                             \
        unpack8(QA, QB, Ah, Al);                                                  \
        acc0 = MFMA16(Ah, BC8(BH0), acc0);                                        \
        acc0 = MFMA16(Al, BC8(BH0), acc0);                                        \
        acc0 = MFMA16(Ah, BC8(BL0), acc0);                                        \
        acc1 = MFMA16(Ah, BC8(BH1), acc1);                                        \
        acc1 = MFMA16(Al, BC8(BH1), acc1);                                        \
        acc1 = MFMA16(Ah, BC8(BL1), acc1);                                        \
    }

__global__ __launch_bounds__(512, 1) void k_seq(const _Float16* __restrict__ Whi,
                                                const _Float16* __restrict__ Wlo,
                                                unsigned int* sbuf, int* flags,
                                                float* out) {
    __shared__ f32x4 pex[8][64];
    int tid = threadIdx.x;
    int w = tid >> 6, l = tid & 63;
    int g = blockIdx.x >> 2, rank = blockIdx.x & 3;
    int kh = w >> 2;
    int kbase = kh * 256;
    int kg4 = l >> 4, kg = kg4 * 4;
    int rowBase = rank * 128;

    // ---- weight preload: 32 named frags ----
    u32x4 h0_0, h0_1, h0_2, h0_3, h0_4, h0_5, h0_6, h0_7;
    u32x4 h1_0, h1_1, h1_2, h1_3, h1_4, h1_5, h1_6, h1_7;
    u32x4 l0_0, l0_1, l0_2, l0_3, l0_4, l0_5, l0_6, l0_7;
    u32x4 l1_0, l1_1, l1_2, l1_3, l1_4, l1_5, l1_6, l1_7;
    {
        int rowA = rowBase + (w & 3) * 32 + (l & 15);
        int rowB = rowA + 16;
        int cb0 = kh * 8;
        size_t foA = (((size_t)rowA * 16 + cb0) * 4 + kg4) * 8;
        size_t foB = (((size_t)rowB * 16 + cb0) * 4 + kg4) * 8;
        LD8W(Whi + foA, h0_0, h0_1, h0_2, h0_3, h0_4, h0_5, h0_6, h0_7);
        LD8W(Whi + foB, h1_0, h1_1, h1_2, h1_3, h1_4, h1_5, h1_6, h1_7);
        LD8W(Wlo + foA, l0_0, l0_1, l0_2, l0_3, l0_4, l0_5, l0_6, l0_7);
        LD8W(Wlo + foB, l1_0, l1_1, l1_2, l1_3, l1_4, l1_5, l1_6, l1_7);
        asm volatile("s_waitcnt vmcnt(0)" ::: "memory");
    }

    int frow = rowBase + (w & 3) * 32 + kh * 16 + (l & 15);
    int bA = g * 16 + (l & 15);
    int* gflags = flags + g * 64;

#pragma unroll 1
    for (int t = 1; t <= 1024; ++t) {
        // ---- prefetch pre-values (own slots; overwritten by us at step end) ----
        float pxw[4];
#pragma unroll
        for (int r = 0; r < 4; ++r) {
            int bG = g * 16 + 4 * (l >> 4) + r;
            pxw[r] = out[(((size_t)bG << 10) + (t - 1)) * 512 + frow];
        }

        // ---- single-wave poll, 4 flags = one line ----
        if (w == 7) {
            for (;;) {
                int a = 0x7fffffff;
                if (l < 4) a = ALOAD(&gflags[l]);
                if (__all(a >= t - 1)) break;
                __builtin_amdgcn_s_sleep(1);
            }
        }
        __syncthreads();  // B1: release all waves

        // ---- state loads: 16 dwordx4, one wait ----
        const unsigned int* rb = sbuf + (size_t)((t - 1) & 1) * STATE_U32;
        const unsigned int* pS = rb + (size_t)bA * 512 + kbase + kg;
        u32x4 q0, q1, q2, q3, q4, q5, q6, q7, q8, q9, q10, q11, q12, q13, q14, q15;
        asm volatile(
            "global_load_dwordx4 %0, %16, off sc1\n\t"
            "global_load_dwordx4 %1, %16, off offset:64 sc1\n\t"
            "global_load_dwordx4 %2, %16, off offset:128 sc1\n\t"
            "global_load_dwordx4 %3, %16, off offset:192 sc1\n\t"
            "global_load_dwordx4 %4, %16, off offset:256 sc1\n\t"
            "global_load_dwordx4 %5, %16, off offset:320 sc1\n\t"
            "global_load_dwordx4 %6, %16, off offset:384 sc1\n\t"
            "global_load_dwordx4 %7, %16, off offset:448 sc1\n\t"
            "global_load_dwordx4 %8, %16, off offset:512 sc1\n\t"
            "global_load_dwordx4 %9, %16, off offset:576 sc1\n\t"
            "global_load_dwordx4 %10, %16, off offset:640 sc1\n\t"
            "global_load_dwordx4 %11, %16, off offset:704 sc1\n\t"
            "global_load_dwordx4 %12, %16, off offset:768 sc1\n\t"
            "global_load_dwordx4 %13, %16, off offset:832 sc1\n\t"
            "global_load_dwordx4 %14, %16, off offset:896 sc1\n\t"
            "global_load_dwordx4 %15, %16, off offset:960 sc1\n\t"
            "s_waitcnt vmcnt(0)"
            : "=&v"(q0), "=&v"(q1), "=&v"(q2), "=&v"(q3), "=&v"(q4), "=&v"(q5),
              "=&v"(q6), "=&v"(q7), "=&v"(q8), "=&v"(q9), "=&v"(q10), "=&v"(q11),
              "=&v"(q12), "=&v"(q13), "=&v"(q14), "=&v"(q15)
            : "v"(pS) : "memory");

        // ---- 48 MFMAs ----
        f32x4 acc0 = (f32x4)0.f, acc1 = (f32x4)0.f;
        KSTEP(q0, q1, h0_0, l0_0, h1_0, l1_0);
        KSTEP(q2, q3, h0_1, l0_1, h1_1, l1_1);
        KSTEP(q4, q5, h0_2, l0_2, h1_2, l1_2);
        KSTEP(q6, q7, h0_3, l0_3, h1_3, l1_3);
        KSTEP(q8, q9, h0_4, l0_4, h1_4, l1_4);
        KSTEP(q10, q11, h0_5, l0_5, h1_5, l1_5);
        KSTEP(q12, q13, h0_6, l0_6, h1_6, l1_6);
        KSTEP(q14, q15, h0_7, l0_7, h1_7, l1_7);

        // ---- pair exchange across K-halves ----
        pex[w][l] = kh ? acc0 : acc1;
        __syncthreads();  // B2
        f32x4 sum = (kh ? acc1 : acc0) + pex[w ^ 4][l];

        // ---- finish: lrelu, store state ----
        unsigned int* wb = sbuf + (size_t)(t & 1) * STATE_U32;
        float vout[4];
#pragma unroll
        for (int r = 0; r < 4; ++r) {
            int bG = g * 16 + 4 * (l >> 4) + r;
            float v = sum[r] + pxw[r];
            v = (v >= 0.f) ? v : 0.2f * v;
            vout[r] = v;
            _Float16 hi = (_Float16)v;
            _Float16 lo = (_Float16)(v - (float)hi);
            unsigned int pr = (unsigned int)__builtin_bit_cast(unsigned short, hi) |
                              ((unsigned int)__builtin_bit_cast(unsigned short, lo) << 16);
            ASTORE(wb + (size_t)bG * 512 + frow, pr);
        }
        asm volatile("s_waitcnt vmcnt(0)" ::: "memory");  // per-wave drain
        __syncthreads();  // B3: all waves' state stores at LLC
        if (tid == 0) ASTORE(&gflags[rank], t);  // single release flag
        // out stores after the flag (off critical path)
#pragma unroll
        for (int r = 0; r < 4; ++r) {
            int bG = g * 16 + 4 * (l >> 4) + r;
            out[(((size_t)bG << 10) + (t - 1)) * 512 + frow] = vout[r];
        }
    }
}

// ---------------------------------------------------------------------------
extern "C" void kernel_launch(void* const* d_in, const int* in_sizes, int n_in,
                              void* d_out, int out_size, void* d_ws, size_t ws_size,
                              hipStream_t stream) {
    const float* x   = (const float*)d_in[0];
    const float* A   = (const float*)d_in[1];
    const float* Bv  = (const float*)d_in[2];
    const float* W_x = (const float*)d_in[3];
    const float* e_x = (const float*)d_in[4];
    const float* W_h = (const float*)d_in[5];
    const float* W_m = (const float*)d_in[6];
    float* out = (float*)d_out;

    char* ws = (char*)d_ws;
    size_t off = 0;
    auto carve = [&](size_t n) -> char* {
        char* p = ws + off;
        off += (n + 255) & ~(size_t)255;
        return p;
    };
    _Float16* Whi   = (_Float16*)carve(512 * 512 * 2);
    _Float16* Wlo   = (_Float16*)carve(512 * 512 * 2);
    _Float16* WxThi = (_Float16*)carve(512 * 128 * 2);
    _Float16* WxTlo = (_Float16*)carve(512 * 128 * 2);
    float* WmT      = (float*)carve(256 * 512 * 4);
    float* AT       = (float*)carve(256 * 256 * 4);
    float* u        = (float*)carve(64 * 1024 * 4);
    unsigned int* sbuf = (unsigned int*)carve(2 * STATE_U32 * 4);
    int* flags      = (int*)carve(4 * 64 * 4);
    float* Apw0     = (float*)carve(256 * 256 * 4);
    float* Apw1     = (float*)carve(256 * 256 * 4);
    float* A64T     = (float*)carve(256 * 256 * 4);
    float* V        = (float*)carve(1024 * 256 * 4);
    _Float16* CThi  = (_Float16*)carve(512 * 1024 * 2);

    // zero state ping-pong + flags (adjacent carves)
    hipMemsetAsync(sbuf, 0, (size_t)2 * STATE_U32 * 4 + 4 * 64 * 4, stream);

    hipLaunchKernelGGL(k_prep, dim3(1536), dim3(256), 0, stream, A, W_x, W_h, W_m,
                       Whi, Wlo, WxThi, WxTlo, WmT, AT);
    hipLaunchKernelGGL(k_u, dim3(256, 64), dim3(256), 0, stream, x, e_x, u);

    // A^2, A^4, A^8, A^16, A^32, A^64 (+A64T)
    hipLaunchKernelGGL(k_a64, dim3(256), dim3(256), 0, stream, A, Apw0, A64T, 0);
    hipLaunchKernelGGL(k_a64, dim3(256), dim3(256), 0, stream, Apw0, Apw1, A64T, 0);
    hipLaunchKernelGGL(k_a64, dim3(256), dim3(256), 0, stream, Apw1, Apw0, A64T, 0);
    hipLaunchKernelGGL(k_a64, dim3(256), dim3(256), 0, stream, Apw0, Apw1, A64T, 0);
    hipLaunchKernelGGL(k_a64, dim3(256), dim3(256), 0, stream, Apw1, Apw0, A64T, 0);
    hipLaunchKernelGGL(k_a64, dim3(256), dim3(256), 0, stream, Apw0, Apw1, A64T, 1);

    hipLaunchKernelGGL(k_vk, dim3(1), dim3(256), 0, stream, AT, Bv, V);
    for (int c = 0; c < 15; ++c)
        hipLaunchKernelGGL(k_vchunk, dim3(64), dim3(256), 0, stream, A64T, V, c);
    hipLaunchKernelGGL(k_c, dim3(1024), dim3(512), 0, stream, V, WmT, CThi);

    hipLaunchKernelGGL(k_preconv, dim3(1024, 2), dim3(256), 0, stream, x, u,
                       WxThi, WxTlo, CThi, out);

    void* args[] = {(void*)&Whi, (void*)&Wlo, (void*)&sbuf, (void*)&flags, (void*)&out};
    hipLaunchCooperativeKernel((void*)k_seq, dim3(16), dim3(512), args, 0, stream);
}

// Round 9
// 5964.618 us; speedup vs baseline: 3.7148x; 1.2325x over previous
//
#include <hip/hip_runtime.h>
#include <stdint.h>

// ---------------------------------------------------------------------------
// KerasLMU — R9.
// m-path = causal conv (R8 structure): W_m m_tau = sum_k c_k u[tau-k],
//   c_k = W_m A^k b; V via k_vk + A^64 chunking; conv fused into pre-GEMM.
//   NEW: CT and WxT stored FRAGMENT-MAJOR -> one dwordx4 per B-frag in
//   k_preconv (R8 used 2 dword loads per frag on a 512-frag/lane hot path).
// Serial chain h-only: h_t = LReLU(pre_t + W_h h_{t-1}), K=512.
// k_seq NEW: tagged-state single-round-trip sync. State element = 8B atom
//   (u32 packed fp16 hi/lo, u32 step tag) stored with ONE relaxed 64-bit
//   atomic store. Consumers speculatively load their slice + tag-check +
//   block-wide vote; the successful load IS the data (no drain, no flags, no
//   fences). Depth-2 ping-pong safe: vote passes only when all 512 rows are
//   at t-1 => every block finished reading t-2. Bounded retry => no hang.
//   Staging: per-wave contiguous 8KB coalesced loads -> swizzled LDS tile
//   (kills the R8 4x same-kh load duplication at the LLC).
// ---------------------------------------------------------------------------

typedef _Float16 half8 __attribute__((ext_vector_type(8)));
typedef float f32x4 __attribute__((ext_vector_type(4)));
typedef unsigned int u32x4 __attribute__((ext_vector_type(4)));
typedef unsigned int u32x2 __attribute__((ext_vector_type(2)));

union H8 { half8 h; unsigned int u[4]; };
union F16 { u32x4 q; half8 h; };

#define MFMA16(a, b, c) __builtin_amdgcn_mfma_f32_16x16x32_f16((a), (b), (c), 0, 0, 0)
#define ALOAD(p) __hip_atomic_load((p), __ATOMIC_RELAXED, __HIP_MEMORY_SCOPE_AGENT)
#define ASTORE64(p, v) __hip_atomic_store((unsigned long long*)(p), (v), \
                                          __ATOMIC_RELAXED, __HIP_MEMORY_SCOPE_AGENT)

__device__ __forceinline__ half8 ld_frag16(const _Float16* W, size_t foff) {
    F16 r;
    r.q = *(const u32x4*)(W + foff);
    return r.h;
}

__device__ __forceinline__ void unpack8(u32x4 A, u32x4 B, half8& hi, half8& lo) {
    H8 h, l;
    h.u[0] = (A[0] & 0xffffu) | (A[1] << 16);  l.u[0] = (A[0] >> 16) | (A[1] & 0xffff0000u);
    h.u[1] = (A[2] & 0xffffu) | (A[3] << 16);  l.u[1] = (A[2] >> 16) | (A[3] & 0xffff0000u);
    h.u[2] = (B[0] & 0xffffu) | (B[1] << 16);  l.u[2] = (B[0] >> 16) | (B[1] & 0xffff0000u);
    h.u[3] = (B[2] & 0xffffu) | (B[3] << 16);  l.u[3] = (B[2] >> 16) | (B[3] & 0xffff0000u);
    hi = h.h; lo = l.h;
}

// ---------------------------------------------------------------------------
// k_prep: W_h fp16 splits FRAGMENT-MAJOR (512x512, 16 col-blocks):
//   idx(r,cb,kgi,e) = ((r*16+cb)*4+kgi)*8+e.
// WxT FRAG-MAJOR (512 rows x 128 K, 4 col-blocks): idx = ((n*4+kt)*4+kgi)*8+e.
// WmT = W_m^T fp32.  AT = A^T fp32.
// ---------------------------------------------------------------------------
__global__ void k_prep(const float* __restrict__ A, const float* __restrict__ W_x,
                       const float* __restrict__ W_h, const float* __restrict__ W_m,
                       _Float16* __restrict__ Whi, _Float16* __restrict__ Wlo,
                       _Float16* __restrict__ WxThi, _Float16* __restrict__ WxTlo,
                       float* __restrict__ WmT, float* __restrict__ AT) {
    int bid = blockIdx.x, tid = threadIdx.x;
    if (bid < 512) {
        int r = bid;
        for (int c = tid; c < 512; c += 256) {
            float v = W_h[(size_t)r * 512 + c];
            _Float16 hi = (_Float16)v;
            _Float16 lo = (_Float16)(v - (float)hi);
            int cb = c >> 5, w = c & 31;
            int kgi = (w & 15) >> 2;
            int e = (w & 3) + ((w & 16) ? 4 : 0);
            size_t idx = (((size_t)r * 16 + cb) * 4 + kgi) * 8 + e;
            Whi[idx] = hi;
            Wlo[idx] = lo;
        }
    } else if (bid < 1024) {
        int n = bid - 512;
        if (tid < 128) {
            int f = tid;
            float v = W_x[(size_t)f * 512 + n];
            _Float16 hi = (_Float16)v;
            _Float16 lo = (_Float16)(v - (float)hi);
            int kt = f >> 5, w = f & 31;
            int kgi = (w & 15) >> 2;
            int e = (w & 3) + ((w & 16) ? 4 : 0);
            size_t idx = (((size_t)n * 4 + kt) * 4 + kgi) * 8 + e;
            WxThi[idx] = hi;
            WxTlo[idx] = lo;
        }
    } else if (bid < 1280) {
        int d = bid - 1024;
        for (int n = tid; n < 512; n += 256)
            WmT[(size_t)d * 512 + n] = W_m[(size_t)n * 256 + d];
    } else {
        int e = bid - 1280;
        if (tid < 256) AT[(size_t)e * 256 + tid] = A[(size_t)tid * 256 + e];
    }
}

// ---------------------------------------------------------------------------
__global__ void k_u(const float* __restrict__ x, const float* __restrict__ e_x,
                    float* __restrict__ u) {
    int wave = threadIdx.x >> 6, l = threadIdx.x & 63;
    int t = blockIdx.x * 4 + wave;
    int b = blockIdx.y;
    const float* xr = x + ((size_t)b * 1025 + t + 1) * 128;
    float s = xr[2 * l] * e_x[2 * l] + xr[2 * l + 1] * e_x[2 * l + 1];
#pragma unroll
    for (int off = 1; off < 64; off <<= 1) s += __shfl_xor(s, off);
    if (l == 0) u[(size_t)b * 1024 + t] = s;
}

// ---------------------------------------------------------------------------
// k_a64: D = S @ S (one squaring). writeT: also D^T into DT.
// ---------------------------------------------------------------------------
__global__ void k_a64(const float* __restrict__ S, float* __restrict__ D,
                      float* __restrict__ DT, int writeT) {
    int r = blockIdx.x, c = threadIdx.x;
    float acc = 0.f;
    for (int e = 0; e < 256; ++e)
        acc += S[(size_t)r * 256 + e] * S[(size_t)e * 256 + c];
    D[(size_t)r * 256 + c] = acc;
    if (writeT) DT[(size_t)c * 256 + r] = acc;
}

// ---------------------------------------------------------------------------
// k_vk: V[k] = A^k b, k=0..63 (serial matvec chain, single block)
// ---------------------------------------------------------------------------
__global__ void k_vk(const float* __restrict__ AT, const float* __restrict__ Bv,
                     float* __restrict__ V) {
    __shared__ float cur[256];
    int tid = threadIdx.x;
    cur[tid] = Bv[tid];
    V[tid] = cur[tid];
    __syncthreads();
    for (int k = 1; k < 64; ++k) {
        float nv = 0.f;
        for (int e = 0; e < 256; ++e) nv += AT[(size_t)e * 256 + tid] * cur[e];
        __syncthreads();
        cur[tid] = nv;
        V[(size_t)k * 256 + tid] = nv;
        __syncthreads();
    }
}

// ---------------------------------------------------------------------------
// k_vchunk: V[(c+1)*64 + j] = A^64 @ V[c*64 + j]
// ---------------------------------------------------------------------------
__global__ void k_vchunk(const float* __restrict__ A64T, float* __restrict__ V,
                         int c) {
    int j = blockIdx.x, d = threadIdx.x;
    const float* vin = V + ((size_t)c * 64 + j) * 256;
    float acc = 0.f;
    for (int e = 0; e < 256; ++e) acc += A64T[(size_t)e * 256 + d] * vin[e];
    V[(((size_t)c + 1) * 64 + j) * 256 + d] = acc;
}

// ---------------------------------------------------------------------------
// k_c: c_k[n] = sum_d V[k][d] W_m[n][d], written FRAGMENT-MAJOR:
//   idx = ((n*32 + ck)*4 + kgi)*8 + e   (K=1024, 32 col-blocks)
// ---------------------------------------------------------------------------
__global__ void k_c(const float* __restrict__ V, const float* __restrict__ WmT,
                    _Float16* __restrict__ CThi) {
    int k = blockIdx.x, n = threadIdx.x;
    const float* vk = V + (size_t)k * 256;
    float acc = 0.f;
    for (int d = 0; d < 256; ++d) acc += vk[d] * WmT[(size_t)d * 512 + n];
    int ck = k >> 5, w = k & 31;
    int kgi = (w & 15) >> 2;
    int e = (w & 3) + ((w & 16) ? 4 : 0);
    CThi[(((size_t)n * 32 + ck) * 4 + kgi) * 8 + e] = (_Float16)acc;
}

// ---------------------------------------------------------------------------
// k_preconv: out[b,tau,n] = x[b,tau+1]@W_x (fp16 3-split, K=128)
//                          + sum_k u[b,tau-k] * c_k[n] (fp16 single, K=1024)
// All B-frags are single dwordx4 loads (fragment-major layouts).
// ---------------------------------------------------------------------------
__global__ __launch_bounds__(256, 1) void k_preconv(const float* __restrict__ x,
                                                    const float* __restrict__ u,
                                                    const _Float16* __restrict__ WxThi,
                                                    const _Float16* __restrict__ WxTlo,
                                                    const _Float16* __restrict__ CThi,
                                                    float* __restrict__ out) {
    __shared__ float xt[64][132];
    __shared__ float ut[1088];
    int tid = threadIdx.x;
    int Mb = blockIdx.x, Nb = blockIdx.y;
    int b = Mb >> 4;
    int t0 = (Mb & 15) * 64;
    const float* src = x + ((size_t)b * 1025 + t0 + 1) * 128;
#pragma unroll
    for (int i = 0; i < 8; ++i) {
        int idx = tid + i * 256;
        int row = idx >> 5, c4 = (idx & 31) * 4;
        *(f32x4*)&xt[row][c4] = *(const f32x4*)(src + (size_t)row * 128 + c4);
    }
    for (int i = tid; i < 1088; i += 256) {
        int tau = t0 - 1024 + i;
        ut[i] = (tau >= 0) ? u[(size_t)b * 1024 + tau] : 0.f;
    }
    __syncthreads();

    int wave = tid >> 6, l = tid & 63;
    int kg4 = l >> 4, kg = kg4 * 4;
    int mrow = wave * 16 + (l & 15);

    half8 ah[4], al[4];
#pragma unroll
    for (int kt = 0; kt < 4; ++kt) {
        f32x4 f0 = *(const f32x4*)&xt[mrow][kt * 32 + kg];
        f32x4 f1 = *(const f32x4*)&xt[mrow][kt * 32 + kg + 16];
        H8 hh, ll;
#pragma unroll
        for (int e = 0; e < 4; ++e) {
            _Float16 h0 = (_Float16)f0[e];
            ((_Float16*)&hh)[e] = h0;
            ((_Float16*)&ll)[e] = (_Float16)(f0[e] - (float)h0);
            _Float16 h1 = (_Float16)f1[e];
            ((_Float16*)&hh)[e + 4] = h1;
            ((_Float16*)&ll)[e + 4] = (_Float16)(f1[e] - (float)h1);
        }
        ah[kt] = hh.h;
        al[kt] = ll.h;
    }

    f32x4 acc[16];
#pragma unroll
    for (int nt = 0; nt < 16; ++nt) acc[nt] = (f32x4)0.f;

    // ---- x @ W_x (3-term split) ----
#pragma unroll
    for (int nt = 0; nt < 16; ++nt) {
        size_t nrow = (size_t)(Nb * 256 + nt * 16 + (l & 15));
#pragma unroll
        for (int kt = 0; kt < 4; ++kt) {
            size_t fo = (((nrow * 4 + kt) * 4 + kg4)) * 8;
            half8 bh = ld_frag16(WxThi, fo);
            half8 bl = ld_frag16(WxTlo, fo);
            acc[nt] = MFMA16(ah[kt], bh, acc[nt]);
            acc[nt] = MFMA16(al[kt], bh, acc[nt]);
            acc[nt] = MFMA16(ah[kt], bl, acc[nt]);
        }
    }

    // ---- Toeplitz(u) @ c  (single fp16, K=1024) ----
    for (int ck = 0; ck < 32; ++ck) {
        int base0 = mrow + 1024 - ck * 32 - kg;
        H8 au;
#pragma unroll
        for (int e = 0; e < 4; ++e) {
            ((_Float16*)&au)[e] = (_Float16)ut[base0 - e];
            ((_Float16*)&au)[e + 4] = (_Float16)ut[base0 - 16 - e];
        }
#pragma unroll
        for (int nt = 0; nt < 16; ++nt) {
            size_t nrow = (size_t)(Nb * 256 + nt * 16 + (l & 15));
            half8 bh = ld_frag16(CThi, (((nrow * 32 + ck) * 4 + kg4)) * 8);
            acc[nt] = MFMA16(au.h, bh, acc[nt]);
        }
    }

#pragma unroll
    for (int nt = 0; nt < 16; ++nt) {
#pragma unroll
        for (int r = 0; r < 4; ++r) {
            size_t bt = (size_t)Mb * 64 + wave * 16 + 4 * (l >> 4) + r;
            out[bt * 512 + Nb * 256 + nt * 16 + (l & 15)] = acc[nt][r];
        }
    }
}

// ---------------------------------------------------------------------------
// k_seq: tagged-state serial chain. 16 blocks (4 groups x 4 ranks) x 512 thr.
// State buffer: [2][64 batches][512 rows] of 8B atoms (value u32, tag u32).
// ---------------------------------------------------------------------------
#define TSTATE_U32 (64 * 512 * 2)

#define LD8W(p, v0, v1, v2, v3, v4, v5, v6, v7)                                   \
    asm volatile("global_load_dwordx4 %0, %8, off\n\t"                            \
                 "global_load_dwordx4 %1, %8, off offset:64\n\t"                  \
                 "global_load_dwordx4 %2, %8, off offset:128\n\t"                 \
                 "global_load_dwordx4 %3, %8, off offset:192\n\t"                 \
                 "global_load_dwordx4 %4, %8, off offset:256\n\t"                 \
                 "global_load_dwordx4 %5, %8, off offset:320\n\t"                 \
                 "global_load_dwordx4 %6, %8, off offset:384\n\t"                 \
                 "global_load_dwordx4 %7, %8, off offset:448"                     \
                 : "=&v"(v0), "=&v"(v1), "=&v"(v2), "=&v"(v3), "=&v"(v4),         \
                   "=&v"(v5), "=&v"(v6), "=&v"(v7)                                \
                 : "v"(p))

#define BC8(x) __builtin_bit_cast(half8, x)

__global__ __launch_bounds__(512, 1) void k_seq(const _Float16* __restrict__ Whi,
                                                const _Float16* __restrict__ Wlo,
                                                unsigned int* sbuf, float* out) {
    __shared__ unsigned int sval[16 * 512];  // 32KB swizzled value tile
    __shared__ f32x4 pex[8][64];
    __shared__ int sh_ok[8];
    __shared__ int sh_all;
    int tid = threadIdx.x;
    int w = tid >> 6, l = tid & 63;
    int g = blockIdx.x >> 2, rank = blockIdx.x & 3;
    int kh = w >> 2;
    int kbase = kh * 256;
    int kg4 = l >> 4, kg = kg4 * 4;
    int rowBase = rank * 128;

    // ---- weight preload: 32 named frags (R8-proven) ----
    u32x4 h0_0, h0_1, h0_2, h0_3, h0_4, h0_5, h0_6, h0_7;
    u32x4 h1_0, h1_1, h1_2, h1_3, h1_4, h1_5, h1_6, h1_7;
    u32x4 l0_0, l0_1, l0_2, l0_3, l0_4, l0_5, l0_6, l0_7;
    u32x4 l1_0, l1_1, l1_2, l1_3, l1_4, l1_5, l1_6, l1_7;
    {
        int rowA = rowBase + (w & 3) * 32 + (l & 15);
        int rowB = rowA + 16;
        int cb0 = kh * 8;
        size_t foA = (((size_t)rowA * 16 + cb0) * 4 + kg4) * 8;
        size_t foB = (((size_t)rowB * 16 + cb0) * 4 + kg4) * 8;
        LD8W(Whi + foA, h0_0, h0_1, h0_2, h0_3, h0_4, h0_5, h0_6, h0_7);
        LD8W(Whi + foB, h1_0, h1_1, h1_2, h1_3, h1_4, h1_5, h1_6, h1_7);
        LD8W(Wlo + foA, l0_0, l0_1, l0_2, l0_3, l0_4, l0_5, l0_6, l0_7);
        LD8W(Wlo + foB, l1_0, l1_1, l1_2, l1_3, l1_4, l1_5, l1_6, l1_7);
        asm volatile("s_waitcnt vmcnt(0)" ::: "memory");
    }

    int frow = rowBase + (w & 3) * 32 + kh * 16 + (l & 15);
    int bX = ((l & 15) & 7) << 2;  // read-side k-swizzle for batch l&15

#pragma unroll 1
    for (int t = 1; t <= 1024; ++t) {
        // ---- prefetch pre-values (own slots, same lane writes them later) ----
        float pxw[4];
#pragma unroll
        for (int r = 0; r < 4; ++r) {
            int bG = g * 16 + 4 * (l >> 4) + r;
            pxw[r] = out[(((size_t)bG << 10) + (t - 1)) * 512 + frow];
        }

        // ---- speculative tagged load of this wave's 8KB slice + vote ----
        const unsigned int* rb = sbuf + (size_t)((t - 1) & 1) * TSTATE_U32;
        const unsigned int* pL0 = rb + ((size_t)g * 8192 + w * 1024) * 2 + l * 4;
        const unsigned int* pL1 = pL0 + 1024;  // +4096B
        u32x4 e0, e1, e2, e3, e4, e5, e6, e7;
        unsigned int exp = (unsigned int)(t - 1);
        int rounds = 0;
        for (;;) {
            asm volatile(
                "global_load_dwordx4 %0, %8, off sc1\n\t"
                "global_load_dwordx4 %1, %8, off offset:1024 sc1\n\t"
                "global_load_dwordx4 %2, %8, off offset:2048 sc1\n\t"
                "global_load_dwordx4 %3, %8, off offset:3072 sc1\n\t"
                "global_load_dwordx4 %4, %9, off sc1\n\t"
                "global_load_dwordx4 %5, %9, off offset:1024 sc1\n\t"
                "global_load_dwordx4 %6, %9, off offset:2048 sc1\n\t"
                "global_load_dwordx4 %7, %9, off offset:3072 sc1\n\t"
                "s_waitcnt vmcnt(0)"
                : "=&v"(e0), "=&v"(e1), "=&v"(e2), "=&v"(e3),
                  "=&v"(e4), "=&v"(e5), "=&v"(e6), "=&v"(e7)
                : "v"(pL0), "v"(pL1) : "memory");
            unsigned int bad =
                (e0[1] ^ exp) | (e0[3] ^ exp) | (e1[1] ^ exp) | (e1[3] ^ exp) |
                (e2[1] ^ exp) | (e2[3] ^ exp) | (e3[1] ^ exp) | (e3[3] ^ exp) |
                (e4[1] ^ exp) | (e4[3] ^ exp) | (e5[1] ^ exp) | (e5[3] ^ exp) |
                (e6[1] ^ exp) | (e6[3] ^ exp) | (e7[1] ^ exp) | (e7[3] ^ exp);
            int wok = __all(bad == 0);
            if (l == 0) sh_ok[w] = wok;
            __syncthreads();
            if (tid == 0)
                sh_all = sh_ok[0] & sh_ok[1] & sh_ok[2] & sh_ok[3] &
                         sh_ok[4] & sh_ok[5] & sh_ok[6] & sh_ok[7];
            __syncthreads();
            if (sh_all) break;
            if (++rounds > 100000) break;  // terminate-not-hang safety net
            __builtin_amdgcn_s_sleep(1);
        }

        // ---- scatter values into swizzled LDS tile ----
        {
            int b0 = w * 2;
            int kb = 2 * l;
            unsigned int* r0 = sval + b0 * 512;
            unsigned int* r1 = sval + (b0 + 1) * 512;
            int X0 = (b0 & 7) << 2, X1 = ((b0 + 1) & 7) << 2;
            *(u32x2*)&r0[(kb) ^ X0]       = (u32x2){e0[0], e0[2]};
            *(u32x2*)&r0[(kb + 128) ^ X0] = (u32x2){e1[0], e1[2]};
            *(u32x2*)&r0[(kb + 256) ^ X0] = (u32x2){e2[0], e2[2]};
            *(u32x2*)&r0[(kb + 384) ^ X0] = (u32x2){e3[0], e3[2]};
            *(u32x2*)&r1[(kb) ^ X1]       = (u32x2){e4[0], e4[2]};
            *(u32x2*)&r1[(kb + 128) ^ X1] = (u32x2){e5[0], e5[2]};
            *(u32x2*)&r1[(kb + 256) ^ X1] = (u32x2){e6[0], e6[2]};
            *(u32x2*)&r1[(kb + 384) ^ X1] = (u32x2){e7[0], e7[2]};
        }
        __syncthreads();

        // ---- frag reads from LDS + 48 MFMAs ----
        const unsigned int* brow = sval + (l & 15) * 512;
        f32x4 acc0 = (f32x4)0.f, acc1 = (f32x4)0.f;
#define RSTEP(KT, BH0, BL0, BH1, BL1)                                             \
        {                                                                         \
            int k0 = kbase + (KT) * 32 + kg;                                      \
            u32x4 qa = *(const u32x4*)&brow[k0 ^ bX];                             \
            u32x4 qb = *(const u32x4*)&brow[(k0 + 16) ^ bX];                      \
            half8 Ah, Al;                                                         \
            unpack8(qa, qb, Ah, Al);                                              \
            acc0 = MFMA16(Ah, BC8(BH0), acc0);                                    \
            acc0 = MFMA16(Al, BC8(BH0), acc0);                                    \
            acc0 = MFMA16(Ah, BC8(BL0), acc0);                                    \
            acc1 = MFMA16(Ah, BC8(BH1), acc1);                                    \
            acc1 = MFMA16(Al, BC8(BH1), acc1);                                    \
            acc1 = MFMA16(Ah, BC8(BL1), acc1);                                    \
        }
        RSTEP(0, h0_0, l0_0, h1_0, l1_0);
        RSTEP(1, h0_1, l0_1, h1_1, l1_1);
        RSTEP(2, h0_2, l0_2, h1_2, l1_2);
        RSTEP(3, h0_3, l0_3, h1_3, l1_3);
        RSTEP(4, h0_4, l0_4, h1_4, l1_4);
        RSTEP(5, h0_5, l0_5, h1_5, l1_5);
        RSTEP(6, h0_6, l0_6, h1_6, l1_6);
        RSTEP(7, h0_7, l0_7, h1_7, l1_7);
#undef RSTEP

        // ---- pair exchange across K-halves ----
        pex[w][l] = kh ? acc0 : acc1;
        __syncthreads();
        f32x4 sum = (kh ? acc1 : acc0) + pex[w ^ 4][l];

        // ---- finish: lrelu, publish tagged state (no drain, no flags) ----
        unsigned int* wbuf = sbuf + (size_t)(t & 1) * TSTATE_U32;
        float vout[4];
#pragma unroll
        for (int r = 0; r < 4; ++r) {
            int bG = g * 16 + 4 * (l >> 4) + r;
            float v = sum[r] + pxw[r];
            v = (v >= 0.f) ? v : 0.2f * v;
            vout[r] = v;
            _Float16 hi = (_Float16)v;
            _Float16 lo = (_Float16)(v - (float)hi);
            unsigned int pr = (unsigned int)__builtin_bit_cast(unsigned short, hi) |
                              ((unsigned int)__builtin_bit_cast(unsigned short, lo) << 16);
            unsigned long long ev =
                (unsigned long long)pr | ((unsigned long long)(unsigned int)t << 32);
            ASTORE64(wbuf + ((size_t)bG * 512 + frow) * 2, ev);
        }
        // out stores fully off the critical path
#pragma unroll
        for (int r = 0; r < 4; ++r) {
            int bG = g * 16 + 4 * (l >> 4) + r;
            out[(((size_t)bG << 10) + (t - 1)) * 512 + frow] = vout[r];
        }
    }
}

// ---------------------------------------------------------------------------
extern "C" void kernel_launch(void* const* d_in, const int* in_sizes, int n_in,
                              void* d_out, int out_size, void* d_ws, size_t ws_size,
                              hipStream_t stream) {
    const float* x   = (const float*)d_in[0];
    const float* A   = (const float*)d_in[1];
    const float* Bv  = (const float*)d_in[2];
    const float* W_x = (const float*)d_in[3];
    const float* e_x = (const float*)d_in[4];
    const float* W_h = (const float*)d_in[5];
    const float* W_m = (const float*)d_in[6];
    float* out = (float*)d_out;

    char* ws = (char*)d_ws;
    size_t off = 0;
    auto carve = [&](size_t n) -> char* {
        char* p = ws + off;
        off += (n + 255) & ~(size_t)255;
        return p;
    };
    _Float16* Whi   = (_Float16*)carve(512 * 512 * 2);
    _Float16* Wlo   = (_Float16*)carve(512 * 512 * 2);
    _Float16* WxThi = (_Float16*)carve(512 * 128 * 2);
    _Float16* WxTlo = (_Float16*)carve(512 * 128 * 2);
    float* WmT      = (float*)carve(256 * 512 * 4);
    float* AT       = (float*)carve(256 * 256 * 4);
    float* u        = (float*)carve(64 * 1024 * 4);
    unsigned int* sbuf = (unsigned int*)carve((size_t)2 * TSTATE_U32 * 4);  // 512KB
    float* Apw0     = (float*)carve(256 * 256 * 4);
    float* Apw1     = (float*)carve(256 * 256 * 4);
    float* A64T     = (float*)carve(256 * 256 * 4);
    float* V        = (float*)carve(1024 * 256 * 4);
    _Float16* CThi  = (_Float16*)carve(512 * 1024 * 2);

    // zero tagged state ping-pong buffers (tags=0 == expected for t=1)
    hipMemsetAsync(sbuf, 0, (size_t)2 * TSTATE_U32 * 4, stream);

    hipLaunchKernelGGL(k_prep, dim3(1536), dim3(256), 0, stream, A, W_x, W_h, W_m,
                       Whi, Wlo, WxThi, WxTlo, WmT, AT);
    hipLaunchKernelGGL(k_u, dim3(256, 64), dim3(256), 0, stream, x, e_x, u);

    // A^2, A^4, A^8, A^16, A^32, A^64 (+A64T)
    hipLaunchKernelGGL(k_a64, dim3(256), dim3(256), 0, stream, A, Apw0, A64T, 0);
    hipLaunchKernelGGL(k_a64, dim3(256), dim3(256), 0, stream, Apw0, Apw1, A64T, 0);
    hipLaunchKernelGGL(k_a64, dim3(256), dim3(256), 0, stream, Apw1, Apw0, A64T, 0);
    hipLaunchKernelGGL(k_a64, dim3(256), dim3(256), 0, stream, Apw0, Apw1, A64T, 0);
    hipLaunchKernelGGL(k_a64, dim3(256), dim3(256), 0, stream, Apw1, Apw0, A64T, 0);
    hipLaunchKernelGGL(k_a64, dim3(256), dim3(256), 0, stream, Apw0, Apw1, A64T, 1);

    hipLaunchKernelGGL(k_vk, dim3(1), dim3(256), 0, stream, AT, Bv, V);
    for (int c = 0; c < 15; ++c)
        hipLaunchKernelGGL(k_vchunk, dim3(64), dim3(256), 0, stream, A64T, V, c);
    hipLaunchKernelGGL(k_c, dim3(1024), dim3(512), 0, stream, V, WmT, CThi);

    hipLaunchKernelGGL(k_preconv, dim3(1024, 2), dim3(256), 0, stream, x, u,
                       WxThi, WxTlo, CThi, out);

    void* args[] = {(void*)&Whi, (void*)&Wlo, (void*)&sbuf, (void*)&out};
    hipLaunchCooperativeKernel((void*)k_seq, dim3(16), dim3(512), args, 0, stream);
}

// Round 10
// 5482.724 us; speedup vs baseline: 4.0413x; 1.0879x over previous
//
#include <hip/hip_runtime.h>
#include <stdint.h>

// ---------------------------------------------------------------------------
// KerasLMU — R10.
// m-path = causal conv (R8/R9 structure): W_m m_tau = sum_k c_k u[tau-k];
//   V via k_vk + fused k_vchain (15 launches -> 1); conv fused into pre-GEMM
//   (k_preconv, fragment-major B).
// Serial chain h-only (K=512), tagged-state single-round-trip sync (R9):
//   8B atoms (value u32 = fp16 hi/lo, tag u32 = step).
// R10 k_seq fixes:
//  (a) per-wave independent retry (own-slice tag check, no block vote, no
//      sleep) -> removes 2 barriers per retry round + sleep quantization.
//  (b) conflict-free LDS scatter: lanes 0-31 stage batch 2w, lanes 32-63
//      stage batch 2w+1 (R9 had all 64 lanes in one row with wave-constant
//      XOR -> 4-way ds_write conflicts, 8.4M conflict cycles/dispatch).
//      Read side (per-batch XOR) unchanged from R9 (proven correct).
// ---------------------------------------------------------------------------

typedef _Float16 half8 __attribute__((ext_vector_type(8)));
typedef float f32x4 __attribute__((ext_vector_type(4)));
typedef unsigned int u32x4 __attribute__((ext_vector_type(4)));
typedef unsigned int u32x2 __attribute__((ext_vector_type(2)));

union H8 { half8 h; unsigned int u[4]; };
union F16 { u32x4 q; half8 h; };

#define MFMA16(a, b, c) __builtin_amdgcn_mfma_f32_16x16x32_f16((a), (b), (c), 0, 0, 0)
#define ASTORE64(p, v) __hip_atomic_store((unsigned long long*)(p), (v), \
                                          __ATOMIC_RELAXED, __HIP_MEMORY_SCOPE_AGENT)

__device__ __forceinline__ half8 ld_frag16(const _Float16* W, size_t foff) {
    F16 r;
    r.q = *(const u32x4*)(W + foff);
    return r.h;
}

__device__ __forceinline__ void unpack8(u32x4 A, u32x4 B, half8& hi, half8& lo) {
    H8 h, l;
    h.u[0] = (A[0] & 0xffffu) | (A[1] << 16);  l.u[0] = (A[0] >> 16) | (A[1] & 0xffff0000u);
    h.u[1] = (A[2] & 0xffffu) | (A[3] << 16);  l.u[1] = (A[2] >> 16) | (A[3] & 0xffff0000u);
    h.u[2] = (B[0] & 0xffffu) | (B[1] << 16);  l.u[2] = (B[0] >> 16) | (B[1] & 0xffff0000u);
    h.u[3] = (B[2] & 0xffffu) | (B[3] << 16);  l.u[3] = (B[2] >> 16) | (B[3] & 0xffff0000u);
    hi = h.h; lo = l.h;
}

// ---------------------------------------------------------------------------
// k_prep: W_h fp16 splits FRAGMENT-MAJOR (512x512, 16 col-blocks):
//   idx(r,cb,kgi,e) = ((r*16+cb)*4+kgi)*8+e.
// WxT FRAG-MAJOR (512 rows x 128 K): idx = ((n*4+kt)*4+kgi)*8+e.
// WmT = W_m^T fp32.  AT = A^T fp32.
// ---------------------------------------------------------------------------
__global__ void k_prep(const float* __restrict__ A, const float* __restrict__ W_x,
                       const float* __restrict__ W_h, const float* __restrict__ W_m,
                       _Float16* __restrict__ Whi, _Float16* __restrict__ Wlo,
                       _Float16* __restrict__ WxThi, _Float16* __restrict__ WxTlo,
                       float* __restrict__ WmT, float* __restrict__ AT) {
    int bid = blockIdx.x, tid = threadIdx.x;
    if (bid < 512) {
        int r = bid;
        for (int c = tid; c < 512; c += 256) {
            float v = W_h[(size_t)r * 512 + c];
            _Float16 hi = (_Float16)v;
            _Float16 lo = (_Float16)(v - (float)hi);
            int cb = c >> 5, w = c & 31;
            int kgi = (w & 15) >> 2;
            int e = (w & 3) + ((w & 16) ? 4 : 0);
            size_t idx = (((size_t)r * 16 + cb) * 4 + kgi) * 8 + e;
            Whi[idx] = hi;
            Wlo[idx] = lo;
        }
    } else if (bid < 1024) {
        int n = bid - 512;
        if (tid < 128) {
            int f = tid;
            float v = W_x[(size_t)f * 512 + n];
            _Float16 hi = (_Float16)v;
            _Float16 lo = (_Float16)(v - (float)hi);
            int kt = f >> 5, w = f & 31;
            int kgi = (w & 15) >> 2;
            int e = (w & 3) + ((w & 16) ? 4 : 0);
            size_t idx = (((size_t)n * 4 + kt) * 4 + kgi) * 8 + e;
            WxThi[idx] = hi;
            WxTlo[idx] = lo;
        }
    } else if (bid < 1280) {
        int d = bid - 1024;
        for (int n = tid; n < 512; n += 256)
            WmT[(size_t)d * 512 + n] = W_m[(size_t)n * 256 + d];
    } else {
        int e = bid - 1280;
        if (tid < 256) AT[(size_t)e * 256 + tid] = A[(size_t)tid * 256 + e];
    }
}

// ---------------------------------------------------------------------------
__global__ void k_u(const float* __restrict__ x, const float* __restrict__ e_x,
                    float* __restrict__ u) {
    int wave = threadIdx.x >> 6, l = threadIdx.x & 63;
    int t = blockIdx.x * 4 + wave;
    int b = blockIdx.y;
    const float* xr = x + ((size_t)b * 1025 + t + 1) * 128;
    float s = xr[2 * l] * e_x[2 * l] + xr[2 * l + 1] * e_x[2 * l + 1];
#pragma unroll
    for (int off = 1; off < 64; off <<= 1) s += __shfl_xor(s, off);
    if (l == 0) u[(size_t)b * 1024 + t] = s;
}

// ---------------------------------------------------------------------------
// k_a64: D = S @ S (one squaring). writeT: also D^T into DT.
// ---------------------------------------------------------------------------
__global__ void k_a64(const float* __restrict__ S, float* __restrict__ D,
                      float* __restrict__ DT, int writeT) {
    int r = blockIdx.x, c = threadIdx.x;
    float acc = 0.f;
    for (int e = 0; e < 256; ++e)
        acc += S[(size_t)r * 256 + e] * S[(size_t)e * 256 + c];
    D[(size_t)r * 256 + c] = acc;
    if (writeT) DT[(size_t)c * 256 + r] = acc;
}

// ---------------------------------------------------------------------------
// k_vk: V[k] = A^k b, k=0..63 (serial matvec chain, single block)
// ---------------------------------------------------------------------------
__global__ void k_vk(const float* __restrict__ AT, const float* __restrict__ Bv,
                     float* __restrict__ V) {
    __shared__ float cur[256];
    int tid = threadIdx.x;
    cur[tid] = Bv[tid];
    V[tid] = cur[tid];
    __syncthreads();
    for (int k = 1; k < 64; ++k) {
        float nv = 0.f;
        for (int e = 0; e < 256; ++e) nv += AT[(size_t)e * 256 + tid] * cur[e];
        __syncthreads();
        cur[tid] = nv;
        V[(size_t)k * 256 + tid] = nv;
        __syncthreads();
    }
}

// ---------------------------------------------------------------------------
// k_vchain: per j (64 blocks), serial c-chain in LDS:
//   V[c*64+j] = A64 @ V[(c-1)*64+j], c=1..15.   (replaces 15 launches)
// ---------------------------------------------------------------------------
__global__ void k_vchain(const float* __restrict__ A64T, float* __restrict__ V) {
    __shared__ float cur[256];
    int j = blockIdx.x, d = threadIdx.x;
    cur[d] = V[(size_t)j * 256 + d];
    __syncthreads();
    for (int c = 1; c < 16; ++c) {
        float nv = 0.f;
        for (int e = 0; e < 256; ++e) nv += A64T[(size_t)e * 256 + d] * cur[e];
        __syncthreads();
        cur[d] = nv;
        V[((size_t)c * 64 + j) * 256 + d] = nv;
        __syncthreads();
    }
}

// ---------------------------------------------------------------------------
// k_c: c_k[n] = sum_d V[k][d] W_m[n][d], FRAGMENT-MAJOR (K=1024, 32 cb):
//   idx = ((n*32 + ck)*4 + kgi)*8 + e
// ---------------------------------------------------------------------------
__global__ void k_c(const float* __restrict__ V, const float* __restrict__ WmT,
                    _Float16* __restrict__ CThi) {
    int k = blockIdx.x, n = threadIdx.x;
    const float* vk = V + (size_t)k * 256;
    float acc = 0.f;
    for (int d = 0; d < 256; ++d) acc += vk[d] * WmT[(size_t)d * 512 + n];
    int ck = k >> 5, w = k & 31;
    int kgi = (w & 15) >> 2;
    int e = (w & 3) + ((w & 16) ? 4 : 0);
    CThi[(((size_t)n * 32 + ck) * 4 + kgi) * 8 + e] = (_Float16)acc;
}

// ---------------------------------------------------------------------------
// k_preconv: out[b,tau,n] = x[b,tau+1]@W_x (fp16 3-split, K=128)
//                          + sum_k u[b,tau-k] * c_k[n] (fp16 single, K=1024)
// ---------------------------------------------------------------------------
__global__ __launch_bounds__(256, 1) void k_preconv(const float* __restrict__ x,
                                                    const float* __restrict__ u,
                                                    const _Float16* __restrict__ WxThi,
                                                    const _Float16* __restrict__ WxTlo,
                                                    const _Float16* __restrict__ CThi,
                                                    float* __restrict__ out) {
    __shared__ float xt[64][132];
    __shared__ float ut[1088];
    int tid = threadIdx.x;
    int Mb = blockIdx.x, Nb = blockIdx.y;
    int b = Mb >> 4;
    int t0 = (Mb & 15) * 64;
    const float* src = x + ((size_t)b * 1025 + t0 + 1) * 128;
#pragma unroll
    for (int i = 0; i < 8; ++i) {
        int idx = tid + i * 256;
        int row = idx >> 5, c4 = (idx & 31) * 4;
        *(f32x4*)&xt[row][c4] = *(const f32x4*)(src + (size_t)row * 128 + c4);
    }
    for (int i = tid; i < 1088; i += 256) {
        int tau = t0 - 1024 + i;
        ut[i] = (tau >= 0) ? u[(size_t)b * 1024 + tau] : 0.f;
    }
    __syncthreads();

    int wave = tid >> 6, l = tid & 63;
    int kg4 = l >> 4, kg = kg4 * 4;
    int mrow = wave * 16 + (l & 15);

    half8 ah[4], al[4];
#pragma unroll
    for (int kt = 0; kt < 4; ++kt) {
        f32x4 f0 = *(const f32x4*)&xt[mrow][kt * 32 + kg];
        f32x4 f1 = *(const f32x4*)&xt[mrow][kt * 32 + kg + 16];
        H8 hh, ll;
#pragma unroll
        for (int e = 0; e < 4; ++e) {
            _Float16 h0 = (_Float16)f0[e];
            ((_Float16*)&hh)[e] = h0;
            ((_Float16*)&ll)[e] = (_Float16)(f0[e] - (float)h0);
            _Float16 h1 = (_Float16)f1[e];
            ((_Float16*)&hh)[e + 4] = h1;
            ((_Float16*)&ll)[e + 4] = (_Float16)(f1[e] - (float)h1);
        }
        ah[kt] = hh.h;
        al[kt] = ll.h;
    }

    f32x4 acc[16];
#pragma unroll
    for (int nt = 0; nt < 16; ++nt) acc[nt] = (f32x4)0.f;

    // ---- x @ W_x (3-term split) ----
#pragma unroll
    for (int nt = 0; nt < 16; ++nt) {
        size_t nrow = (size_t)(Nb * 256 + nt * 16 + (l & 15));
#pragma unroll
        for (int kt = 0; kt < 4; ++kt) {
            size_t fo = (((nrow * 4 + kt) * 4 + kg4)) * 8;
            half8 bh = ld_frag16(WxThi, fo);
            half8 bl = ld_frag16(WxTlo, fo);
            acc[nt] = MFMA16(ah[kt], bh, acc[nt]);
            acc[nt] = MFMA16(al[kt], bh, acc[nt]);
            acc[nt] = MFMA16(ah[kt], bl, acc[nt]);
        }
    }

    // ---- Toeplitz(u) @ c  (single fp16, K=1024) ----
    for (int ck = 0; ck < 32; ++ck) {
        int base0 = mrow + 1024 - ck * 32 - kg;
        H8 au;
#pragma unroll
        for (int e = 0; e < 4; ++e) {
            ((_Float16*)&au)[e] = (_Float16)ut[base0 - e];
            ((_Float16*)&au)[e + 4] = (_Float16)ut[base0 - 16 - e];
        }
#pragma unroll
        for (int nt = 0; nt < 16; ++nt) {
            size_t nrow = (size_t)(Nb * 256 + nt * 16 + (l & 15));
            half8 bh = ld_frag16(CThi, (((nrow * 32 + ck) * 4 + kg4)) * 8);
            acc[nt] = MFMA16(au.h, bh, acc[nt]);
        }
    }

#pragma unroll
    for (int nt = 0; nt < 16; ++nt) {
#pragma unroll
        for (int r = 0; r < 4; ++r) {
            size_t bt = (size_t)Mb * 64 + wave * 16 + 4 * (l >> 4) + r;
            out[bt * 512 + Nb * 256 + nt * 16 + (l & 15)] = acc[nt][r];
        }
    }
}

// ---------------------------------------------------------------------------
// k_seq: tagged-state serial chain. 16 blocks (4 groups x 4 ranks) x 512 thr.
// State: [2][64 batches][512 rows] 8B atoms (value u32, tag u32).
// Staging: lanes 0-31 stage batch 2w, lanes 32-63 stage batch 2w+1.
// ---------------------------------------------------------------------------
#define TSTATE_U32 (64 * 512 * 2)

#define LD8W(p, v0, v1, v2, v3, v4, v5, v6, v7)                                   \
    asm volatile("global_load_dwordx4 %0, %8, off\n\t"                            \
                 "global_load_dwordx4 %1, %8, off offset:64\n\t"                  \
                 "global_load_dwordx4 %2, %8, off offset:128\n\t"                 \
                 "global_load_dwordx4 %3, %8, off offset:192\n\t"                 \
                 "global_load_dwordx4 %4, %8, off offset:256\n\t"                 \
                 "global_load_dwordx4 %5, %8, off offset:320\n\t"                 \
                 "global_load_dwordx4 %6, %8, off offset:384\n\t"                 \
                 "global_load_dwordx4 %7, %8, off offset:448"                     \
                 : "=&v"(v0), "=&v"(v1), "=&v"(v2), "=&v"(v3), "=&v"(v4),         \
                   "=&v"(v5), "=&v"(v6), "=&v"(v7)                                \
                 : "v"(p))

#define BC8(x) __builtin_bit_cast(half8, x)

__global__ __launch_bounds__(512, 1) void k_seq(const _Float16* __restrict__ Whi,
                                                const _Float16* __restrict__ Wlo,
                                                unsigned int* sbuf, float* out) {
    __shared__ unsigned int sval[16 * 512];  // 32KB swizzled value tile
    __shared__ f32x4 pex[8][64];
    int tid = threadIdx.x;
    int w = tid >> 6, l = tid & 63;
    int g = blockIdx.x >> 2, rank = blockIdx.x & 3;
    int kh = w >> 2;
    int kbase = kh * 256;
    int kg4 = l >> 4, kg = kg4 * 4;
    int rowBase = rank * 128;

    // ---- weight preload: 32 named frags (proven) ----
    u32x4 h0_0, h0_1, h0_2, h0_3, h0_4, h0_5, h0_6, h0_7;
    u32x4 h1_0, h1_1, h1_2, h1_3, h1_4, h1_5, h1_6, h1_7;
    u32x4 l0_0, l0_1, l0_2, l0_3, l0_4, l0_5, l0_6, l0_7;
    u32x4 l1_0, l1_1, l1_2, l1_3, l1_4, l1_5, l1_6, l1_7;
    {
        int rowA = rowBase + (w & 3) * 32 + (l & 15);
        int rowB = rowA + 16;
        int cb0 = kh * 8;
        size_t foA = (((size_t)rowA * 16 + cb0) * 4 + kg4) * 8;
        size_t foB = (((size_t)rowB * 16 + cb0) * 4 + kg4) * 8;
        LD8W(Whi + foA, h0_0, h0_1, h0_2, h0_3, h0_4, h0_5, h0_6, h0_7);
        LD8W(Whi + foB, h1_0, h1_1, h1_2, h1_3, h1_4, h1_5, h1_6, h1_7);
        LD8W(Wlo + foA, l0_0, l0_1, l0_2, l0_3, l0_4, l0_5, l0_6, l0_7);
        LD8W(Wlo + foB, l1_0, l1_1, l1_2, l1_3, l1_4, l1_5, l1_6, l1_7);
        asm volatile("s_waitcnt vmcnt(0)" ::: "memory");
    }

    int frow = rowBase + (w & 3) * 32 + kh * 16 + (l & 15);
    int bX = ((l & 15) & 7) << 2;          // read-side per-batch XOR
    int bloc = 2 * w + (l >> 5);           // staged local batch (0..15)
    unsigned int sX = (unsigned int)((bloc & 7) << 2);  // write-side XOR
    int lam = l & 31;

#pragma unroll 1
    for (int t = 1; t <= 1024; ++t) {
        // ---- prefetch pre-values (own slots, same lane writes them later) ----
        float pxw[4];
#pragma unroll
        for (int r = 0; r < 4; ++r) {
            int bG = g * 16 + 4 * (l >> 4) + r;
            pxw[r] = out[(((size_t)bG << 10) + (t - 1)) * 512 + frow];
        }

        // ---- per-wave speculative tagged load + own-slice check (no vote) ----
        const unsigned int* rb = sbuf + (size_t)((t - 1) & 1) * TSTATE_U32;
        const unsigned int* pL =
            rb + (size_t)(g * 16 + bloc) * 1024 + (size_t)lam * 4;
        u32x4 e0, e1, e2, e3, e4, e5, e6, e7;
        unsigned int exp = (unsigned int)(t - 1);
        int rounds = 0;
        for (;;) {
            asm volatile(
                "global_load_dwordx4 %0, %8, off sc1\n\t"
                "global_load_dwordx4 %1, %8, off offset:512 sc1\n\t"
                "global_load_dwordx4 %2, %8, off offset:1024 sc1\n\t"
                "global_load_dwordx4 %3, %8, off offset:1536 sc1\n\t"
                "global_load_dwordx4 %4, %8, off offset:2048 sc1\n\t"
                "global_load_dwordx4 %5, %8, off offset:2560 sc1\n\t"
                "global_load_dwordx4 %6, %8, off offset:3072 sc1\n\t"
                "global_load_dwordx4 %7, %8, off offset:3584 sc1\n\t"
                "s_waitcnt vmcnt(0)"
                : "=&v"(e0), "=&v"(e1), "=&v"(e2), "=&v"(e3),
                  "=&v"(e4), "=&v"(e5), "=&v"(e6), "=&v"(e7)
                : "v"(pL) : "memory");
            unsigned int bad =
                (e0[1] ^ exp) | (e0[3] ^ exp) | (e1[1] ^ exp) | (e1[3] ^ exp) |
                (e2[1] ^ exp) | (e2[3] ^ exp) | (e3[1] ^ exp) | (e3[3] ^ exp) |
                (e4[1] ^ exp) | (e4[3] ^ exp) | (e5[1] ^ exp) | (e5[3] ^ exp) |
                (e6[1] ^ exp) | (e6[3] ^ exp) | (e7[1] ^ exp) | (e7[3] ^ exp);
            if (__all(bad == 0)) break;
            if (++rounds > 200000) break;  // terminate-not-hang safety net
        }

        // ---- scatter into swizzled LDS tile (2-way free banks) ----
        {
            unsigned int* row = sval + bloc * 512;
            int kb = 2 * lam;
            *(u32x2*)&row[(kb)       ^ sX] = (u32x2){e0[0], e0[2]};
            *(u32x2*)&row[(kb + 64)  ^ sX] = (u32x2){e1[0], e1[2]};
            *(u32x2*)&row[(kb + 128) ^ sX] = (u32x2){e2[0], e2[2]};
            *(u32x2*)&row[(kb + 192) ^ sX] = (u32x2){e3[0], e3[2]};
            *(u32x2*)&row[(kb + 256) ^ sX] = (u32x2){e4[0], e4[2]};
            *(u32x2*)&row[(kb + 320) ^ sX] = (u32x2){e5[0], e5[2]};
            *(u32x2*)&row[(kb + 384) ^ sX] = (u32x2){e6[0], e6[2]};
            *(u32x2*)&row[(kb + 448) ^ sX] = (u32x2){e7[0], e7[2]};
        }
        __syncthreads();  // BAR-A: staging complete

        // ---- frag reads from LDS + 48 MFMAs ----
        const unsigned int* brow = sval + (l & 15) * 512;
        f32x4 acc0 = (f32x4)0.f, acc1 = (f32x4)0.f;
#define RSTEP(KT, BH0, BL0, BH1, BL1)                                             \
        {                                                                         \
            int k0 = kbase + (KT) * 32 + kg;                                      \
            u32x4 qa = *(const u32x4*)&brow[k0 ^ bX];                             \
            u32x4 qb = *(const u32x4*)&brow[(k0 + 16) ^ bX];                      \
            half8 Ah, Al;                                                         \
            unpack8(qa, qb, Ah, Al);                                              \
            acc0 = MFMA16(Ah, BC8(BH0), acc0);                                    \
            acc0 = MFMA16(Al, BC8(BH0), acc0);                                    \
            acc0 = MFMA16(Ah, BC8(BL0), acc0);                                    \
            acc1 = MFMA16(Ah, BC8(BH1), acc1);                                    \
            acc1 = MFMA16(Al, BC8(BH1), acc1);                                    \
            acc1 = MFMA16(Ah, BC8(BL1), acc1);                                    \
        }
        RSTEP(0, h0_0, l0_0, h1_0, l1_0);
        RSTEP(1, h0_1, l0_1, h1_1, l1_1);
        RSTEP(2, h0_2, l0_2, h1_2, l1_2);
        RSTEP(3, h0_3, l0_3, h1_3, l1_3);
        RSTEP(4, h0_4, l0_4, h1_4, l1_4);
        RSTEP(5, h0_5, l0_5, h1_5, l1_5);
        RSTEP(6, h0_6, l0_6, h1_6, l1_6);
        RSTEP(7, h0_7, l0_7, h1_7, l1_7);
#undef RSTEP

        // ---- pair exchange across K-halves ----
        pex[w][l] = kh ? acc0 : acc1;
        __syncthreads();  // BAR-B
        f32x4 sum = (kh ? acc1 : acc0) + pex[w ^ 4][l];

        // ---- finish: lrelu, publish tagged state (no drain, no flags) ----
        unsigned int* wbuf = sbuf + (size_t)(t & 1) * TSTATE_U32;
        float vout[4];
#pragma unroll
        for (int r = 0; r < 4; ++r) {
            int bG = g * 16 + 4 * (l >> 4) + r;
            float v = sum[r] + pxw[r];
            v = (v >= 0.f) ? v : 0.2f * v;
            vout[r] = v;
            _Float16 hi = (_Float16)v;
            _Float16 lo = (_Float16)(v - (float)hi);
            unsigned int pr = (unsigned int)__builtin_bit_cast(unsigned short, hi) |
                              ((unsigned int)__builtin_bit_cast(unsigned short, lo) << 16);
            unsigned long long ev =
                (unsigned long long)pr | ((unsigned long long)(unsigned int)t << 32);
            ASTORE64(wbuf + ((size_t)bG * 512 + frow) * 2, ev);
        }
        // out stores fully off the critical path
#pragma unroll
        for (int r = 0; r < 4; ++r) {
            int bG = g * 16 + 4 * (l >> 4) + r;
            out[(((size_t)bG << 10) + (t - 1)) * 512 + frow] = vout[r];
        }
    }
}

// ---------------------------------------------------------------------------
extern "C" void kernel_launch(void* const* d_in, const int* in_sizes, int n_in,
                              void* d_out, int out_size, void* d_ws, size_t ws_size,
                              hipStream_t stream) {
    const float* x   = (const float*)d_in[0];
    const float* A   = (const float*)d_in[1];
    const float* Bv  = (const float*)d_in[2];
    const float* W_x = (const float*)d_in[3];
    const float* e_x = (const float*)d_in[4];
    const float* W_h = (const float*)d_in[5];
    const float* W_m = (const float*)d_in[6];
    float* out = (float*)d_out;

    char* ws = (char*)d_ws;
    size_t off = 0;
    auto carve = [&](size_t n) -> char* {
        char* p = ws + off;
        off += (n + 255) & ~(size_t)255;
        return p;
    };
    _Float16* Whi   = (_Float16*)carve(512 * 512 * 2);
    _Float16* Wlo   = (_Float16*)carve(512 * 512 * 2);
    _Float16* WxThi = (_Float16*)carve(512 * 128 * 2);
    _Float16* WxTlo = (_Float16*)carve(512 * 128 * 2);
    float* WmT      = (float*)carve(256 * 512 * 4);
    float* AT       = (float*)carve(256 * 256 * 4);
    float* u        = (float*)carve(64 * 1024 * 4);
    unsigned int* sbuf = (unsigned int*)carve((size_t)2 * TSTATE_U32 * 4);  // 512KB
    float* Apw0     = (float*)carve(256 * 256 * 4);
    float* Apw1     = (float*)carve(256 * 256 * 4);
    float* A64T     = (float*)carve(256 * 256 * 4);
    float* V        = (float*)carve(1024 * 256 * 4);
    _Float16* CThi  = (_Float16*)carve(512 * 1024 * 2);

    // zero tagged state ping-pong buffers (tags=0 == expected for t=1)
    hipMemsetAsync(sbuf, 0, (size_t)2 * TSTATE_U32 * 4, stream);

    hipLaunchKernelGGL(k_prep, dim3(1536), dim3(256), 0, stream, A, W_x, W_h, W_m,
                       Whi, Wlo, WxThi, WxTlo, WmT, AT);
    hipLaunchKernelGGL(k_u, dim3(256, 64), dim3(256), 0, stream, x, e_x, u);

    // A^2, A^4, A^8, A^16, A^32, A^64 (+A64T)
    hipLaunchKernelGGL(k_a64, dim3(256), dim3(256), 0, stream, A, Apw0, A64T, 0);
    hipLaunchKernelGGL(k_a64, dim3(256), dim3(256), 0, stream, Apw0, Apw1, A64T, 0);
    hipLaunchKernelGGL(k_a64, dim3(256), dim3(256), 0, stream, Apw1, Apw0, A64T, 0);
    hipLaunchKernelGGL(k_a64, dim3(256), dim3(256), 0, stream, Apw0, Apw1, A64T, 0);
    hipLaunchKernelGGL(k_a64, dim3(256), dim3(256), 0, stream, Apw1, Apw0, A64T, 0);
    hipLaunchKernelGGL(k_a64, dim3(256), dim3(256), 0, stream, Apw0, Apw1, A64T, 1);

    hipLaunchKernelGGL(k_vk, dim3(1), dim3(256), 0, stream, AT, Bv, V);
    hipLaunchKernelGGL(k_vchain, dim3(64), dim3(256), 0, stream, A64T, V);
    hipLaunchKernelGGL(k_c, dim3(1024), dim3(512), 0, stream, V, WmT, CThi);

    hipLaunchKernelGGL(k_preconv, dim3(1024, 2), dim3(256), 0, stream, x, u,
                       WxThi, WxTlo, CThi, out);

    void* args[] = {(void*)&Whi, (void*)&Wlo, (void*)&sbuf, (void*)&out};
    hipLaunchCooperativeKernel((void*)k_seq, dim3(16), dim3(512), args, 0, stream);
}

// Round 11
// 5216.504 us; speedup vs baseline: 4.2475x; 1.0510x over previous
//
#include <hip/hip_runtime.h>
#include <stdint.h>

// ---------------------------------------------------------------------------
// KerasLMU — R11.
// m-path = causal conv (R8-R10): W_m m_tau = sum_k c_k u[tau-k]; conv fused
//   into pre-GEMM (k_preconv, fragment-major B).  Unchanged from R10.
// Serial chain h-only (K=512), tagged-state single-round-trip sync (R9/R10):
//   8B atoms (value u32 = fp16 hi/lo, tag u32 = step).
// R11 k_seq changes (protocol & staging verbatim from R10):
//  (a) 8 blocks/group (32 blocks): 64 rows/block, 16 rows x K-half per wave,
//      24 MFMA/wave/step (was 48), 16 weight frags/lane (was 32). Finish
//      split by batch-half (kh wave stores r in {2kh,2kh+1}).
//  (b) retry round-0 PRE-ISSUED at the previous step's finish (after tagged
//      stores) -> overlaps pex/finish/out-stores; top-of-loop vmcnt(0)+check
//      (sched_barrier(0) after waitcnt per rule: stops VALU hoisting).
// ---------------------------------------------------------------------------

typedef _Float16 half8 __attribute__((ext_vector_type(8)));
typedef float f32x4 __attribute__((ext_vector_type(4)));
typedef unsigned int u32x4 __attribute__((ext_vector_type(4)));
typedef unsigned int u32x2 __attribute__((ext_vector_type(2)));

union H8 { half8 h; unsigned int u[4]; };
union F16 { u32x4 q; half8 h; };

#define MFMA16(a, b, c) __builtin_amdgcn_mfma_f32_16x16x32_f16((a), (b), (c), 0, 0, 0)
#define ASTORE64(p, v) __hip_atomic_store((unsigned long long*)(p), (v), \
                                          __ATOMIC_RELAXED, __HIP_MEMORY_SCOPE_AGENT)

__device__ __forceinline__ half8 ld_frag16(const _Float16* W, size_t foff) {
    F16 r;
    r.q = *(const u32x4*)(W + foff);
    return r.h;
}

__device__ __forceinline__ void unpack8(u32x4 A, u32x4 B, half8& hi, half8& lo) {
    H8 h, l;
    h.u[0] = (A[0] & 0xffffu) | (A[1] << 16);  l.u[0] = (A[0] >> 16) | (A[1] & 0xffff0000u);
    h.u[1] = (A[2] & 0xffffu) | (A[3] << 16);  l.u[1] = (A[2] >> 16) | (A[3] & 0xffff0000u);
    h.u[2] = (B[0] & 0xffffu) | (B[1] << 16);  l.u[2] = (B[0] >> 16) | (B[1] & 0xffff0000u);
    h.u[3] = (B[2] & 0xffffu) | (B[3] << 16);  l.u[3] = (B[2] >> 16) | (B[3] & 0xffff0000u);
    hi = h.h; lo = l.h;
}

// ---------------------------------------------------------------------------
// k_prep: W_h fp16 splits FRAGMENT-MAJOR (512x512, 16 col-blocks):
//   idx(r,cb,kgi,e) = ((r*16+cb)*4+kgi)*8+e.
// WxT FRAG-MAJOR (512 rows x 128 K): idx = ((n*4+kt)*4+kgi)*8+e.
// WmT = W_m^T fp32.  AT = A^T fp32.
// ---------------------------------------------------------------------------
__global__ void k_prep(const float* __restrict__ A, const float* __restrict__ W_x,
                       const float* __restrict__ W_h, const float* __restrict__ W_m,
                       _Float16* __restrict__ Whi, _Float16* __restrict__ Wlo,
                       _Float16* __restrict__ WxThi, _Float16* __restrict__ WxTlo,
                       float* __restrict__ WmT, float* __restrict__ AT) {
    int bid = blockIdx.x, tid = threadIdx.x;
    if (bid < 512) {
        int r = bid;
        for (int c = tid; c < 512; c += 256) {
            float v = W_h[(size_t)r * 512 + c];
            _Float16 hi = (_Float16)v;
            _Float16 lo = (_Float16)(v - (float)hi);
            int cb = c >> 5, w = c & 31;
            int kgi = (w & 15) >> 2;
            int e = (w & 3) + ((w & 16) ? 4 : 0);
            size_t idx = (((size_t)r * 16 + cb) * 4 + kgi) * 8 + e;
            Whi[idx] = hi;
            Wlo[idx] = lo;
        }
    } else if (bid < 1024) {
        int n = bid - 512;
        if (tid < 128) {
            int f = tid;
            float v = W_x[(size_t)f * 512 + n];
            _Float16 hi = (_Float16)v;
            _Float16 lo = (_Float16)(v - (float)hi);
            int kt = f >> 5, w = f & 31;
            int kgi = (w & 15) >> 2;
            int e = (w & 3) + ((w & 16) ? 4 : 0);
            size_t idx = (((size_t)n * 4 + kt) * 4 + kgi) * 8 + e;
            WxThi[idx] = hi;
            WxTlo[idx] = lo;
        }
    } else if (bid < 1280) {
        int d = bid - 1024;
        for (int n = tid; n < 512; n += 256)
            WmT[(size_t)d * 512 + n] = W_m[(size_t)n * 256 + d];
    } else {
        int e = bid - 1280;
        if (tid < 256) AT[(size_t)e * 256 + tid] = A[(size_t)tid * 256 + e];
    }
}

// ---------------------------------------------------------------------------
__global__ void k_u(const float* __restrict__ x, const float* __restrict__ e_x,
                    float* __restrict__ u) {
    int wave = threadIdx.x >> 6, l = threadIdx.x & 63;
    int t = blockIdx.x * 4 + wave;
    int b = blockIdx.y;
    const float* xr = x + ((size_t)b * 1025 + t + 1) * 128;
    float s = xr[2 * l] * e_x[2 * l] + xr[2 * l + 1] * e_x[2 * l + 1];
#pragma unroll
    for (int off = 1; off < 64; off <<= 1) s += __shfl_xor(s, off);
    if (l == 0) u[(size_t)b * 1024 + t] = s;
}

// ---------------------------------------------------------------------------
// k_a64: D = S @ S (one squaring). writeT: also D^T into DT.
// ---------------------------------------------------------------------------
__global__ void k_a64(const float* __restrict__ S, float* __restrict__ D,
                      float* __restrict__ DT, int writeT) {
    int r = blockIdx.x, c = threadIdx.x;
    float acc = 0.f;
    for (int e = 0; e < 256; ++e)
        acc += S[(size_t)r * 256 + e] * S[(size_t)e * 256 + c];
    D[(size_t)r * 256 + c] = acc;
    if (writeT) DT[(size_t)c * 256 + r] = acc;
}

// ---------------------------------------------------------------------------
// k_vk: V[k] = A^k b, k=0..63 (serial matvec chain, single block)
// ---------------------------------------------------------------------------
__global__ void k_vk(const float* __restrict__ AT, const float* __restrict__ Bv,
                     float* __restrict__ V) {
    __shared__ float cur[256];
    int tid = threadIdx.x;
    cur[tid] = Bv[tid];
    V[tid] = cur[tid];
    __syncthreads();
    for (int k = 1; k < 64; ++k) {
        float nv = 0.f;
        for (int e = 0; e < 256; ++e) nv += AT[(size_t)e * 256 + tid] * cur[e];
        __syncthreads();
        cur[tid] = nv;
        V[(size_t)k * 256 + tid] = nv;
        __syncthreads();
    }
}

// ---------------------------------------------------------------------------
// k_vchain: per j (64 blocks), serial c-chain in LDS:
//   V[c*64+j] = A64 @ V[(c-1)*64+j], c=1..15.
// ---------------------------------------------------------------------------
__global__ void k_vchain(const float* __restrict__ A64T, float* __restrict__ V) {
    __shared__ float cur[256];
    int j = blockIdx.x, d = threadIdx.x;
    cur[d] = V[(size_t)j * 256 + d];
    __syncthreads();
    for (int c = 1; c < 16; ++c) {
        float nv = 0.f;
        for (int e = 0; e < 256; ++e) nv += A64T[(size_t)e * 256 + d] * cur[e];
        __syncthreads();
        cur[d] = nv;
        V[((size_t)c * 64 + j) * 256 + d] = nv;
        __syncthreads();
    }
}

// ---------------------------------------------------------------------------
// k_c: c_k[n] = sum_d V[k][d] W_m[n][d], FRAGMENT-MAJOR (K=1024, 32 cb):
//   idx = ((n*32 + ck)*4 + kgi)*8 + e
// ---------------------------------------------------------------------------
__global__ void k_c(const float* __restrict__ V, const float* __restrict__ WmT,
                    _Float16* __restrict__ CThi) {
    int k = blockIdx.x, n = threadIdx.x;
    const float* vk = V + (size_t)k * 256;
    float acc = 0.f;
    for (int d = 0; d < 256; ++d) acc += vk[d] * WmT[(size_t)d * 512 + n];
    int ck = k >> 5, w = k & 31;
    int kgi = (w & 15) >> 2;
    int e = (w & 3) + ((w & 16) ? 4 : 0);
    CThi[(((size_t)n * 32 + ck) * 4 + kgi) * 8 + e] = (_Float16)acc;
}

// ---------------------------------------------------------------------------
// k_preconv: out[b,tau,n] = x[b,tau+1]@W_x (fp16 3-split, K=128)
//                          + sum_k u[b,tau-k] * c_k[n] (fp16 single, K=1024)
// ---------------------------------------------------------------------------
__global__ __launch_bounds__(256, 1) void k_preconv(const float* __restrict__ x,
                                                    const float* __restrict__ u,
                                                    const _Float16* __restrict__ WxThi,
                                                    const _Float16* __restrict__ WxTlo,
                                                    const _Float16* __restrict__ CThi,
                                                    float* __restrict__ out) {
    __shared__ float xt[64][132];
    __shared__ float ut[1088];
    int tid = threadIdx.x;
    int Mb = blockIdx.x, Nb = blockIdx.y;
    int b = Mb >> 4;
    int t0 = (Mb & 15) * 64;
    const float* src = x + ((size_t)b * 1025 + t0 + 1) * 128;
#pragma unroll
    for (int i = 0; i < 8; ++i) {
        int idx = tid + i * 256;
        int row = idx >> 5, c4 = (idx & 31) * 4;
        *(f32x4*)&xt[row][c4] = *(const f32x4*)(src + (size_t)row * 128 + c4);
    }
    for (int i = tid; i < 1088; i += 256) {
        int tau = t0 - 1024 + i;
        ut[i] = (tau >= 0) ? u[(size_t)b * 1024 + tau] : 0.f;
    }
    __syncthreads();

    int wave = tid >> 6, l = tid & 63;
    int kg4 = l >> 4, kg = kg4 * 4;
    int mrow = wave * 16 + (l & 15);

    half8 ah[4], al[4];
#pragma unroll
    for (int kt = 0; kt < 4; ++kt) {
        f32x4 f0 = *(const f32x4*)&xt[mrow][kt * 32 + kg];
        f32x4 f1 = *(const f32x4*)&xt[mrow][kt * 32 + kg + 16];
        H8 hh, ll;
#pragma unroll
        for (int e = 0; e < 4; ++e) {
            _Float16 h0 = (_Float16)f0[e];
            ((_Float16*)&hh)[e] = h0;
            ((_Float16*)&ll)[e] = (_Float16)(f0[e] - (float)h0);
            _Float16 h1 = (_Float16)f1[e];
            ((_Float16*)&hh)[e + 4] = h1;
            ((_Float16*)&ll)[e + 4] = (_Float16)(f1[e] - (float)h1);
        }
        ah[kt] = hh.h;
        al[kt] = ll.h;
    }

    f32x4 acc[16];
#pragma unroll
    for (int nt = 0; nt < 16; ++nt) acc[nt] = (f32x4)0.f;

    // ---- x @ W_x (3-term split) ----
#pragma unroll
    for (int nt = 0; nt < 16; ++nt) {
        size_t nrow = (size_t)(Nb * 256 + nt * 16 + (l & 15));
#pragma unroll
        for (int kt = 0; kt < 4; ++kt) {
            size_t fo = (((nrow * 4 + kt) * 4 + kg4)) * 8;
            half8 bh = ld_frag16(WxThi, fo);
            half8 bl = ld_frag16(WxTlo, fo);
            acc[nt] = MFMA16(ah[kt], bh, acc[nt]);
            acc[nt] = MFMA16(al[kt], bh, acc[nt]);
            acc[nt] = MFMA16(ah[kt], bl, acc[nt]);
        }
    }

    // ---- Toeplitz(u) @ c  (single fp16, K=1024) ----
    for (int ck = 0; ck < 32; ++ck) {
        int base0 = mrow + 1024 - ck * 32 - kg;
        H8 au;
#pragma unroll
        for (int e = 0; e < 4; ++e) {
            ((_Float16*)&au)[e] = (_Float16)ut[base0 - e];
            ((_Float16*)&au)[e + 4] = (_Float16)ut[base0 - 16 - e];
        }
#pragma unroll
        for (int nt = 0; nt < 16; ++nt) {
            size_t nrow = (size_t)(Nb * 256 + nt * 16 + (l & 15));
            half8 bh = ld_frag16(CThi, (((nrow * 32 + ck) * 4 + kg4)) * 8);
            acc[nt] = MFMA16(au.h, bh, acc[nt]);
        }
    }

#pragma unroll
    for (int nt = 0; nt < 16; ++nt) {
#pragma unroll
        for (int r = 0; r < 4; ++r) {
            size_t bt = (size_t)Mb * 64 + wave * 16 + 4 * (l >> 4) + r;
            out[bt * 512 + Nb * 256 + nt * 16 + (l & 15)] = acc[nt][r];
        }
    }
}

// ---------------------------------------------------------------------------
// k_seq: tagged-state serial chain. 32 blocks (4 groups x 8 ranks) x 512 thr.
// State: [2][64 batches][512 rows] 8B atoms (value u32, tag u32).
// Wave w: rows rank*64 + (w&3)*16, K-half kh=w>>2. Finish r in {2kh,2kh+1}.
// ---------------------------------------------------------------------------
#define TSTATE_U32 (64 * 512 * 2)

#define LD8W(p, v0, v1, v2, v3, v4, v5, v6, v7)                                   \
    asm volatile("global_load_dwordx4 %0, %8, off\n\t"                            \
                 "global_load_dwordx4 %1, %8, off offset:64\n\t"                  \
                 "global_load_dwordx4 %2, %8, off offset:128\n\t"                 \
                 "global_load_dwordx4 %3, %8, off offset:192\n\t"                 \
                 "global_load_dwordx4 %4, %8, off offset:256\n\t"                 \
                 "global_load_dwordx4 %5, %8, off offset:320\n\t"                 \
                 "global_load_dwordx4 %6, %8, off offset:384\n\t"                 \
                 "global_load_dwordx4 %7, %8, off offset:448"                     \
                 : "=&v"(v0), "=&v"(v1), "=&v"(v2), "=&v"(v3), "=&v"(v4),         \
                   "=&v"(v5), "=&v"(v6), "=&v"(v7)                                \
                 : "v"(p))

// issue 8 state loads (4KB slice), NO waitcnt -- caller waits.
#define ISSUE_STATE(p)                                                            \
    asm volatile("global_load_dwordx4 %0, %8, off sc1\n\t"                        \
                 "global_load_dwordx4 %1, %8, off offset:512 sc1\n\t"             \
                 "global_load_dwordx4 %2, %8, off offset:1024 sc1\n\t"            \
                 "global_load_dwordx4 %3, %8, off offset:1536 sc1\n\t"            \
                 "global_load_dwordx4 %4, %8, off offset:2048 sc1\n\t"            \
                 "global_load_dwordx4 %5, %8, off offset:2560 sc1\n\t"            \
                 "global_load_dwordx4 %6, %8, off offset:3072 sc1\n\t"            \
                 "global_load_dwordx4 %7, %8, off offset:3584 sc1"                \
                 : "=&v"(e0), "=&v"(e1), "=&v"(e2), "=&v"(e3),                    \
                   "=&v"(e4), "=&v"(e5), "=&v"(e6), "=&v"(e7)                     \
                 : "v"(p) : "memory")

#define VM0_FENCE()                                                               \
    do {                                                                          \
        asm volatile("s_waitcnt vmcnt(0)" ::: "memory");                          \
        __builtin_amdgcn_sched_barrier(0);                                        \
    } while (0)

#define TAGBAD(exp)                                                               \
    ((e0[1] ^ (exp)) | (e0[3] ^ (exp)) | (e1[1] ^ (exp)) | (e1[3] ^ (exp)) |      \
     (e2[1] ^ (exp)) | (e2[3] ^ (exp)) | (e3[1] ^ (exp)) | (e3[3] ^ (exp)) |      \
     (e4[1] ^ (exp)) | (e4[3] ^ (exp)) | (e5[1] ^ (exp)) | (e5[3] ^ (exp)) |      \
     (e6[1] ^ (exp)) | (e6[3] ^ (exp)) | (e7[1] ^ (exp)) | (e7[3] ^ (exp)))

#define BC8(x) __builtin_bit_cast(half8, x)

__global__ __launch_bounds__(512, 1) void k_seq(const _Float16* __restrict__ Whi,
                                                const _Float16* __restrict__ Wlo,
                                                unsigned int* sbuf, float* out) {
    __shared__ unsigned int sval[16 * 512];  // 32KB swizzled value tile
    __shared__ f32x4 pex[8][64];
    int tid = threadIdx.x;
    int w = tid >> 6, l = tid & 63;
    int g = blockIdx.x >> 3, rank = blockIdx.x & 7;
    int kh = w >> 2;
    int kbase = kh * 256;
    int kg4 = l >> 4, kg = kg4 * 4;

    // ---- weight preload: 16 named frags (16 rows x K-half) ----
    u32x4 wh0, wh1, wh2, wh3, wh4, wh5, wh6, wh7;
    u32x4 wl0, wl1, wl2, wl3, wl4, wl5, wl6, wl7;
    int frow = rank * 64 + (w & 3) * 16 + (l & 15);
    {
        size_t fo = (((size_t)frow * 16 + kh * 8) * 4 + kg4) * 8;
        LD8W(Whi + fo, wh0, wh1, wh2, wh3, wh4, wh5, wh6, wh7);
        LD8W(Wlo + fo, wl0, wl1, wl2, wl3, wl4, wl5, wl6, wl7);
        asm volatile("s_waitcnt vmcnt(0)" ::: "memory");
    }

    int bX = ((l & 15) & 7) << 2;          // read-side per-batch XOR
    int bloc = 2 * w + (l >> 5);           // staged local batch (0..15)
    unsigned int sX = (unsigned int)((bloc & 7) << 2);  // write-side XOR
    int lam = l & 31;
    size_t soff = (size_t)(g * 16 + bloc) * 1024 + (size_t)lam * 4;

    u32x4 e0, e1, e2, e3, e4, e5, e6, e7;
    // ---- prologue: pre-issue round-0 for t=1 (buffer 0) ----
    ISSUE_STATE(sbuf + soff);

#pragma unroll 1
    for (int t = 1; t <= 1024; ++t) {
        // ---- prefetch pre-values for the 2 batches this wave finishes ----
        float pxw0, pxw1;
        {
            int r0 = 2 * kh;
            int bG0 = g * 16 + 4 * (l >> 4) + r0;
            pxw0 = out[(((size_t)bG0 << 10) + (t - 1)) * 512 + frow];
            pxw1 = out[(((size_t)(bG0 + 1) << 10) + (t - 1)) * 512 + frow];
        }

        // ---- check pre-issued round-0; retry until own slice tagged t-1 ----
        const unsigned int* pL = sbuf + (size_t)((t - 1) & 1) * TSTATE_U32 + soff;
        unsigned int exp = (unsigned int)(t - 1);
        VM0_FENCE();
        unsigned int bad = TAGBAD(exp);
        int rounds = 0;
        while (!__all(bad == 0)) {
            if (++rounds > 200000) break;  // terminate-not-hang safety net
            ISSUE_STATE(pL);
            VM0_FENCE();
            bad = TAGBAD(exp);
        }

        // ---- scatter into swizzled LDS tile ----
        {
            unsigned int* row = sval + bloc * 512;
            int kb = 2 * lam;
            *(u32x2*)&row[(kb)       ^ sX] = (u32x2){e0[0], e0[2]};
            *(u32x2*)&row[(kb + 64)  ^ sX] = (u32x2){e1[0], e1[2]};
            *(u32x2*)&row[(kb + 128) ^ sX] = (u32x2){e2[0], e2[2]};
            *(u32x2*)&row[(kb + 192) ^ sX] = (u32x2){e3[0], e3[2]};
            *(u32x2*)&row[(kb + 256) ^ sX] = (u32x2){e4[0], e4[2]};
            *(u32x2*)&row[(kb + 320) ^ sX] = (u32x2){e5[0], e5[2]};
            *(u32x2*)&row[(kb + 384) ^ sX] = (u32x2){e6[0], e6[2]};
            *(u32x2*)&row[(kb + 448) ^ sX] = (u32x2){e7[0], e7[2]};
        }
        __syncthreads();  // BAR-A: staging complete

        // ---- frag reads from LDS + 24 MFMAs ----
        const unsigned int* brow = sval + (l & 15) * 512;
        f32x4 acc = (f32x4)0.f;
#define RSTEP(KT, BH, BL)                                                         \
        {                                                                         \
            int k0 = kbase + (KT) * 32 + kg;                                      \
            u32x4 qa = *(const u32x4*)&brow[k0 ^ bX];                             \
            u32x4 qb = *(const u32x4*)&brow[(k0 + 16) ^ bX];                      \
            half8 Ah, Al;                                                         \
            unpack8(qa, qb, Ah, Al);                                              \
            acc = MFMA16(Ah, BC8(BH), acc);                                       \
            acc = MFMA16(Al, BC8(BH), acc);                                       \
            acc = MFMA16(Ah, BC8(BL), acc);                                       \
        }
        RSTEP(0, wh0, wl0);
        RSTEP(1, wh1, wl1);
        RSTEP(2, wh2, wl2);
        RSTEP(3, wh3, wl3);
        RSTEP(4, wh4, wl4);
        RSTEP(5, wh5, wl5);
        RSTEP(6, wh6, wl6);
        RSTEP(7, wh7, wl7);
#undef RSTEP

        // ---- pair exchange across K-halves (full acc) ----
        pex[w][l] = acc;
        __syncthreads();  // BAR-B
        f32x4 sum = acc + pex[w ^ 4][l];

        // ---- finish: this wave stores batches r = 2kh, 2kh+1 ----
        float s0 = kh ? sum[2] : sum[0];
        float s1 = kh ? sum[3] : sum[1];
        unsigned int* wbuf = sbuf + (size_t)(t & 1) * TSTATE_U32;
        int bG0 = g * 16 + 4 * (l >> 4) + 2 * kh;
        float v0 = s0 + pxw0;
        v0 = (v0 >= 0.f) ? v0 : 0.2f * v0;
        float v1 = s1 + pxw1;
        v1 = (v1 >= 0.f) ? v1 : 0.2f * v1;
        {
            _Float16 hi0 = (_Float16)v0, lo0 = (_Float16)(v0 - (float)hi0);
            _Float16 hi1 = (_Float16)v1, lo1 = (_Float16)(v1 - (float)hi1);
            unsigned int p0 = (unsigned int)__builtin_bit_cast(unsigned short, hi0) |
                              ((unsigned int)__builtin_bit_cast(unsigned short, lo0) << 16);
            unsigned int p1 = (unsigned int)__builtin_bit_cast(unsigned short, hi1) |
                              ((unsigned int)__builtin_bit_cast(unsigned short, lo1) << 16);
            unsigned long long t64 = (unsigned long long)(unsigned int)t << 32;
            ASTORE64(wbuf + ((size_t)bG0 * 512 + frow) * 2, (unsigned long long)p0 | t64);
            ASTORE64(wbuf + ((size_t)(bG0 + 1) * 512 + frow) * 2,
                     (unsigned long long)p1 | t64);
        }
        // ---- pre-issue round-0 for step t+1 (overlaps out stores / loopback)
        ISSUE_STATE(sbuf + (size_t)(t & 1) * TSTATE_U32 + soff);
        // ---- out stores fully off the critical path ----
        out[(((size_t)bG0 << 10) + (t - 1)) * 512 + frow] = v0;
        out[(((size_t)(bG0 + 1) << 10) + (t - 1)) * 512 + frow] = v1;
    }
}

// ---------------------------------------------------------------------------
extern "C" void kernel_launch(void* const* d_in, const int* in_sizes, int n_in,
                              void* d_out, int out_size, void* d_ws, size_t ws_size,
                              hipStream_t stream) {
    const float* x   = (const float*)d_in[0];
    const float* A   = (const float*)d_in[1];
    const float* Bv  = (const float*)d_in[2];
    const float* W_x = (const float*)d_in[3];
    const float* e_x = (const float*)d_in[4];
    const float* W_h = (const float*)d_in[5];
    const float* W_m = (const float*)d_in[6];
    float* out = (float*)d_out;

    char* ws = (char*)d_ws;
    size_t off = 0;
    auto carve = [&](size_t n) -> char* {
        char* p = ws + off;
        off += (n + 255) & ~(size_t)255;
        return p;
    };
    _Float16* Whi   = (_Float16*)carve(512 * 512 * 2);
    _Float16* Wlo   = (_Float16*)carve(512 * 512 * 2);
    _Float16* WxThi = (_Float16*)carve(512 * 128 * 2);
    _Float16* WxTlo = (_Float16*)carve(512 * 128 * 2);
    float* WmT      = (float*)carve(256 * 512 * 4);
    float* AT       = (float*)carve(256 * 256 * 4);
    float* u        = (float*)carve(64 * 1024 * 4);
    unsigned int* sbuf = (unsigned int*)carve((size_t)2 * TSTATE_U32 * 4);  // 512KB
    float* Apw0     = (float*)carve(256 * 256 * 4);
    float* Apw1     = (float*)carve(256 * 256 * 4);
    float* A64T     = (float*)carve(256 * 256 * 4);
    float* V        = (float*)carve(1024 * 256 * 4);
    _Float16* CThi  = (_Float16*)carve(512 * 1024 * 2);

    // zero tagged state ping-pong buffers (tags=0 == expected for t=1)
    hipMemsetAsync(sbuf, 0, (size_t)2 * TSTATE_U32 * 4, stream);

    hipLaunchKernelGGL(k_prep, dim3(1536), dim3(256), 0, stream, A, W_x, W_h, W_m,
                       Whi, Wlo, WxThi, WxTlo, WmT, AT);
    hipLaunchKernelGGL(k_u, dim3(256, 64), dim3(256), 0, stream, x, e_x, u);

    // A^2, A^4, A^8, A^16, A^32, A^64 (+A64T)
    hipLaunchKernelGGL(k_a64, dim3(256), dim3(256), 0, stream, A, Apw0, A64T, 0);
    hipLaunchKernelGGL(k_a64, dim3(256), dim3(256), 0, stream, Apw0, Apw1, A64T, 0);
    hipLaunchKernelGGL(k_a64, dim3(256), dim3(256), 0, stream, Apw1, Apw0, A64T, 0);
    hipLaunchKernelGGL(k_a64, dim3(256), dim3(256), 0, stream, Apw0, Apw1, A64T, 0);
    hipLaunchKernelGGL(k_a64, dim3(256), dim3(256), 0, stream, Apw1, Apw0, A64T, 0);
    hipLaunchKernelGGL(k_a64, dim3(256), dim3(256), 0, stream, Apw0, Apw1, A64T, 1);

    hipLaunchKernelGGL(k_vk, dim3(1), dim3(256), 0, stream, AT, Bv, V);
    hipLaunchKernelGGL(k_vchain, dim3(64), dim3(256), 0, stream, A64T, V);
    hipLaunchKernelGGL(k_c, dim3(1024), dim3(512), 0, stream, V, WmT, CThi);

    hipLaunchKernelGGL(k_preconv, dim3(1024, 2), dim3(256), 0, stream, x, u,
                       WxThi, WxTlo, CThi, out);

    void* args[] = {(void*)&Whi, (void*)&Wlo, (void*)&sbuf, (void*)&out};
    hipLaunchCooperativeKernel((void*)k_seq, dim3(32), dim3(512), args, 0, stream);
}

// Round 13
// 5092.530 us; speedup vs baseline: 4.3510x; 1.0243x over previous
//
#include <hip/hip_runtime.h>
#include <stdint.h>

// ---------------------------------------------------------------------------
// KerasLMU — R13 (bisect round).
// k_seq: REVERTED to R11-exact (VM0 full fence at loop top, pxw loads inside
//   the iteration) — the configuration proven at 4196us / absmax 0.03125.
//   R12's vmcnt(2) counted fence + npxw pipelining is backed out: it relied
//   on unverified in-order vmcnt retirement across mixed loads/stores.
// Precompute: KEPT at R12-new (V doubling chain, restructured k_c) to bisect
//   which R12 change broke correctness.
// ---------------------------------------------------------------------------

typedef _Float16 half8 __attribute__((ext_vector_type(8)));
typedef float f32x4 __attribute__((ext_vector_type(4)));
typedef unsigned int u32x4 __attribute__((ext_vector_type(4)));
typedef unsigned int u32x2 __attribute__((ext_vector_type(2)));

union H8 { half8 h; unsigned int u[4]; };
union F16 { u32x4 q; half8 h; };

#define MFMA16(a, b, c) __builtin_amdgcn_mfma_f32_16x16x32_f16((a), (b), (c), 0, 0, 0)
#define ASTORE64(p, v) __hip_atomic_store((unsigned long long*)(p), (v), \
                                          __ATOMIC_RELAXED, __HIP_MEMORY_SCOPE_AGENT)

__device__ __forceinline__ half8 ld_frag16(const _Float16* W, size_t foff) {
    F16 r;
    r.q = *(const u32x4*)(W + foff);
    return r.h;
}

__device__ __forceinline__ void unpack8(u32x4 A, u32x4 B, half8& hi, half8& lo) {
    H8 h, l;
    h.u[0] = (A[0] & 0xffffu) | (A[1] << 16);  l.u[0] = (A[0] >> 16) | (A[1] & 0xffff0000u);
    h.u[1] = (A[2] & 0xffffu) | (A[3] << 16);  l.u[1] = (A[2] >> 16) | (A[3] & 0xffff0000u);
    h.u[2] = (B[0] & 0xffffu) | (B[1] << 16);  l.u[2] = (B[0] >> 16) | (B[1] & 0xffff0000u);
    h.u[3] = (B[2] & 0xffffu) | (B[3] << 16);  l.u[3] = (B[2] >> 16) | (B[3] & 0xffff0000u);
    hi = h.h; lo = l.h;
}

// ---------------------------------------------------------------------------
// k_prep: W_h fp16 splits FRAGMENT-MAJOR; WxT FRAG-MAJOR; AT = A^T; V0 = b.
// ---------------------------------------------------------------------------
__global__ void k_prep(const float* __restrict__ A, const float* __restrict__ Bv,
                       const float* __restrict__ W_x, const float* __restrict__ W_h,
                       _Float16* __restrict__ Whi, _Float16* __restrict__ Wlo,
                       _Float16* __restrict__ WxThi, _Float16* __restrict__ WxTlo,
                       float* __restrict__ AT, float* __restrict__ V) {
    int bid = blockIdx.x, tid = threadIdx.x;
    if (bid < 512) {
        int r = bid;
        for (int c = tid; c < 512; c += 256) {
            float v = W_h[(size_t)r * 512 + c];
            _Float16 hi = (_Float16)v;
            _Float16 lo = (_Float16)(v - (float)hi);
            int cb = c >> 5, w = c & 31;
            int kgi = (w & 15) >> 2;
            int e = (w & 3) + ((w & 16) ? 4 : 0);
            size_t idx = (((size_t)r * 16 + cb) * 4 + kgi) * 8 + e;
            Whi[idx] = hi;
            Wlo[idx] = lo;
        }
    } else if (bid < 1024) {
        int n = bid - 512;
        if (tid < 128) {
            int f = tid;
            float v = W_x[(size_t)f * 512 + n];
            _Float16 hi = (_Float16)v;
            _Float16 lo = (_Float16)(v - (float)hi);
            int kt = f >> 5, w = f & 31;
            int kgi = (w & 15) >> 2;
            int e = (w & 3) + ((w & 16) ? 4 : 0);
            size_t idx = (((size_t)n * 4 + kt) * 4 + kgi) * 8 + e;
            WxThi[idx] = hi;
            WxTlo[idx] = lo;
        }
    } else if (bid < 1280) {
        int e = bid - 1024;
        if (tid < 256) AT[(size_t)e * 256 + tid] = A[(size_t)tid * 256 + e];
    } else {
        if (tid < 256) V[tid] = Bv[tid];
    }
}

// ---------------------------------------------------------------------------
__global__ void k_u(const float* __restrict__ x, const float* __restrict__ e_x,
                    float* __restrict__ u) {
    int wave = threadIdx.x >> 6, l = threadIdx.x & 63;
    int t = blockIdx.x * 4 + wave;
    int b = blockIdx.y;
    const float* xr = x + ((size_t)b * 1025 + t + 1) * 128;
    float s = xr[2 * l] * e_x[2 * l] + xr[2 * l + 1] * e_x[2 * l + 1];
#pragma unroll
    for (int off = 1; off < 64; off <<= 1) s += __shfl_xor(s, off);
    if (l == 0) u[(size_t)b * 1024 + t] = s;
}

// ---------------------------------------------------------------------------
// k_a64: D = S @ S (one squaring), DT = D^T (always).
// ---------------------------------------------------------------------------
__global__ void k_a64(const float* __restrict__ S, float* __restrict__ D,
                      float* __restrict__ DT) {
    int r = blockIdx.x, c = threadIdx.x;
    float acc = 0.f;
    for (int e = 0; e < 256; ++e)
        acc += S[(size_t)r * 256 + e] * S[(size_t)e * 256 + c];
    D[(size_t)r * 256 + c] = acc;
    DT[(size_t)c * 256 + r] = acc;
}

// ---------------------------------------------------------------------------
// k_vdouble: V[base + j0] = P @ V[j0], j0 in [0, base)  (PT = P^T).
// ---------------------------------------------------------------------------
__global__ void k_vdouble(const float* __restrict__ PT, float* __restrict__ V,
                          int base) {
    __shared__ float cur[256];
    int j0 = blockIdx.x, d = threadIdx.x;
    cur[d] = V[(size_t)j0 * 256 + d];
    __syncthreads();
    float acc = 0.f;
    for (int e = 0; e < 256; ++e) acc += PT[(size_t)e * 256 + d] * cur[e];
    V[(size_t)(base + j0) * 256 + d] = acc;
}

// ---------------------------------------------------------------------------
// k_vchain: per j (64 blocks), serial c-chain: V[c*64+j] = A64 @ V[(c-1)*64+j]
// ---------------------------------------------------------------------------
__global__ void k_vchain(const float* __restrict__ A64T, float* __restrict__ V) {
    __shared__ float cur[256];
    int j = blockIdx.x, d = threadIdx.x;
    cur[d] = V[(size_t)j * 256 + d];
    __syncthreads();
    for (int c = 1; c < 16; ++c) {
        float nv = 0.f;
        for (int e = 0; e < 256; ++e) nv += A64T[(size_t)e * 256 + d] * cur[e];
        __syncthreads();
        cur[d] = nv;
        V[((size_t)c * 64 + j) * 256 + d] = nv;
        __syncthreads();
    }
}

// ---------------------------------------------------------------------------
// k_c: c_k[n] = sum_d V[k][d] W_m[n][d], FRAGMENT-MAJOR out.
// 64 blocks x 256 thr; block owns 8 n-rows (W_m rows staged in LDS).
// ---------------------------------------------------------------------------
__global__ void k_c(const float* __restrict__ V, const float* __restrict__ W_m,
                    _Float16* __restrict__ CThi) {
    __shared__ float wm[8][260];
    int bid = blockIdx.x, tid = threadIdx.x;
    for (int i = tid; i < 8 * 256; i += 256)
        wm[i >> 8][i & 255] = W_m[(size_t)(bid * 8 + (i >> 8)) * 256 + (i & 255)];
    __syncthreads();
    for (int j = 0; j < 4; ++j) {
        int k = tid + 256 * j;
        const f32x4* vk = (const f32x4*)(V + (size_t)k * 256);
        float a[8];
#pragma unroll
        for (int n = 0; n < 8; ++n) a[n] = 0.f;
        for (int d4 = 0; d4 < 64; ++d4) {
            f32x4 vv = vk[d4];
#pragma unroll
            for (int n = 0; n < 8; ++n)
                a[n] += vv[0] * wm[n][d4 * 4] + vv[1] * wm[n][d4 * 4 + 1] +
                        vv[2] * wm[n][d4 * 4 + 2] + vv[3] * wm[n][d4 * 4 + 3];
        }
        int ck = k >> 5, w = k & 31;
        int kgi = (w & 15) >> 2;
        int e = (w & 3) + ((w & 16) ? 4 : 0);
#pragma unroll
        for (int n = 0; n < 8; ++n) {
            size_t nn = (size_t)(bid * 8 + n);
            CThi[((nn * 32 + ck) * 4 + kgi) * 8 + e] = (_Float16)a[n];
        }
    }
}

// ---------------------------------------------------------------------------
// k_preconv: out[b,tau,n] = x[b,tau+1]@W_x (fp16 3-split, K=128)
//                          + sum_k u[b,tau-k] * c_k[n] (fp16 single, K=1024)
// ---------------------------------------------------------------------------
__global__ __launch_bounds__(256, 1) void k_preconv(const float* __restrict__ x,
                                                    const float* __restrict__ u,
                                                    const _Float16* __restrict__ WxThi,
                                                    const _Float16* __restrict__ WxTlo,
                                                    const _Float16* __restrict__ CThi,
                                                    float* __restrict__ out) {
    __shared__ float xt[64][132];
    __shared__ float ut[1088];
    int tid = threadIdx.x;
    int Mb = blockIdx.x, Nb = blockIdx.y;
    int b = Mb >> 4;
    int t0 = (Mb & 15) * 64;
    const float* src = x + ((size_t)b * 1025 + t0 + 1) * 128;
#pragma unroll
    for (int i = 0; i < 8; ++i) {
        int idx = tid + i * 256;
        int row = idx >> 5, c4 = (idx & 31) * 4;
        *(f32x4*)&xt[row][c4] = *(const f32x4*)(src + (size_t)row * 128 + c4);
    }
    for (int i = tid; i < 1088; i += 256) {
        int tau = t0 - 1024 + i;
        ut[i] = (tau >= 0) ? u[(size_t)b * 1024 + tau] : 0.f;
    }
    __syncthreads();

    int wave = tid >> 6, l = tid & 63;
    int kg4 = l >> 4, kg = kg4 * 4;
    int mrow = wave * 16 + (l & 15);

    half8 ah[4], al[4];
#pragma unroll
    for (int kt = 0; kt < 4; ++kt) {
        f32x4 f0 = *(const f32x4*)&xt[mrow][kt * 32 + kg];
        f32x4 f1 = *(const f32x4*)&xt[mrow][kt * 32 + kg + 16];
        H8 hh, ll;
#pragma unroll
        for (int e = 0; e < 4; ++e) {
            _Float16 h0 = (_Float16)f0[e];
            ((_Float16*)&hh)[e] = h0;
            ((_Float16*)&ll)[e] = (_Float16)(f0[e] - (float)h0);
            _Float16 h1 = (_Float16)f1[e];
            ((_Float16*)&hh)[e + 4] = h1;
            ((_Float16*)&ll)[e + 4] = (_Float16)(f1[e] - (float)h1);
        }
        ah[kt] = hh.h;
        al[kt] = ll.h;
    }

    f32x4 acc[16];
#pragma unroll
    for (int nt = 0; nt < 16; ++nt) acc[nt] = (f32x4)0.f;

    // ---- x @ W_x (3-term split) ----
#pragma unroll
    for (int nt = 0; nt < 16; ++nt) {
        size_t nrow = (size_t)(Nb * 256 + nt * 16 + (l & 15));
#pragma unroll
        for (int kt = 0; kt < 4; ++kt) {
            size_t fo = (((nrow * 4 + kt) * 4 + kg4)) * 8;
            half8 bh = ld_frag16(WxThi, fo);
            half8 bl = ld_frag16(WxTlo, fo);
            acc[nt] = MFMA16(ah[kt], bh, acc[nt]);
            acc[nt] = MFMA16(al[kt], bh, acc[nt]);
            acc[nt] = MFMA16(ah[kt], bl, acc[nt]);
        }
    }

    // ---- Toeplitz(u) @ c  (single fp16, K=1024) ----
    for (int ck = 0; ck < 32; ++ck) {
        int base0 = mrow + 1024 - ck * 32 - kg;
        H8 au;
#pragma unroll
        for (int e = 0; e < 4; ++e) {
            ((_Float16*)&au)[e] = (_Float16)ut[base0 - e];
            ((_Float16*)&au)[e + 4] = (_Float16)ut[base0 - 16 - e];
        }
#pragma unroll
        for (int nt = 0; nt < 16; ++nt) {
            size_t nrow = (size_t)(Nb * 256 + nt * 16 + (l & 15));
            half8 bh = ld_frag16(CThi, (((nrow * 32 + ck) * 4 + kg4)) * 8);
            acc[nt] = MFMA16(au.h, bh, acc[nt]);
        }
    }

#pragma unroll
    for (int nt = 0; nt < 16; ++nt) {
#pragma unroll
        for (int r = 0; r < 4; ++r) {
            size_t bt = (size_t)Mb * 64 + wave * 16 + 4 * (l >> 4) + r;
            out[bt * 512 + Nb * 256 + nt * 16 + (l & 15)] = acc[nt][r];
        }
    }
}

// ---------------------------------------------------------------------------
// k_seq: tagged-state serial chain. 32 blocks (4 groups x 8 ranks) x 512 thr.
// R11-EXACT (VM0 full fence, pxw loads inside the iteration).
// ---------------------------------------------------------------------------
#define TSTATE_U32 (64 * 512 * 2)

#define LD8W(p, v0, v1, v2, v3, v4, v5, v6, v7)                                   \
    asm volatile("global_load_dwordx4 %0, %8, off\n\t"                            \
                 "global_load_dwordx4 %1, %8, off offset:64\n\t"                  \
                 "global_load_dwordx4 %2, %8, off offset:128\n\t"                 \
                 "global_load_dwordx4 %3, %8, off offset:192\n\t"                 \
                 "global_load_dwordx4 %4, %8, off offset:256\n\t"                 \
                 "global_load_dwordx4 %5, %8, off offset:320\n\t"                 \
                 "global_load_dwordx4 %6, %8, off offset:384\n\t"                 \
                 "global_load_dwordx4 %7, %8, off offset:448"                     \
                 : "=&v"(v0), "=&v"(v1), "=&v"(v2), "=&v"(v3), "=&v"(v4),         \
                   "=&v"(v5), "=&v"(v6), "=&v"(v7)                                \
                 : "v"(p))

#define ISSUE_STATE(p)                                                            \
    asm volatile("global_load_dwordx4 %0, %8, off sc1\n\t"                        \
                 "global_load_dwordx4 %1, %8, off offset:512 sc1\n\t"             \
                 "global_load_dwordx4 %2, %8, off offset:1024 sc1\n\t"            \
                 "global_load_dwordx4 %3, %8, off offset:1536 sc1\n\t"            \
                 "global_load_dwordx4 %4, %8, off offset:2048 sc1\n\t"            \
                 "global_load_dwordx4 %5, %8, off offset:2560 sc1\n\t"            \
                 "global_load_dwordx4 %6, %8, off offset:3072 sc1\n\t"            \
                 "global_load_dwordx4 %7, %8, off offset:3584 sc1"                \
                 : "=&v"(e0), "=&v"(e1), "=&v"(e2), "=&v"(e3),                    \
                   "=&v"(e4), "=&v"(e5), "=&v"(e6), "=&v"(e7)                     \
                 : "v"(p) : "memory")

#define VM0_FENCE()                                                               \
    do {                                                                          \
        asm volatile("s_waitcnt vmcnt(0)" ::: "memory");                          \
        __builtin_amdgcn_sched_barrier(0);                                        \
    } while (0)

#define TAGBAD(exp)                                                               \
    ((e0[1] ^ (exp)) | (e0[3] ^ (exp)) | (e1[1] ^ (exp)) | (e1[3] ^ (exp)) |      \
     (e2[1] ^ (exp)) | (e2[3] ^ (exp)) | (e3[1] ^ (exp)) | (e3[3] ^ (exp)) |      \
     (e4[1] ^ (exp)) | (e4[3] ^ (exp)) | (e5[1] ^ (exp)) | (e5[3] ^ (exp)) |      \
     (e6[1] ^ (exp)) | (e6[3] ^ (exp)) | (e7[1] ^ (exp)) | (e7[3] ^ (exp)))

#define BC8(x) __builtin_bit_cast(half8, x)

__global__ __launch_bounds__(512, 1) void k_seq(const _Float16* __restrict__ Whi,
                                                const _Float16* __restrict__ Wlo,
                                                unsigned int* sbuf, float* out) {
    __shared__ unsigned int sval[16 * 512];  // 32KB swizzled value tile
    __shared__ f32x4 pex[8][64];
    int tid = threadIdx.x;
    int w = tid >> 6, l = tid & 63;
    int g = blockIdx.x >> 3, rank = blockIdx.x & 7;
    int kh = w >> 2;
    int kbase = kh * 256;
    int kg4 = l >> 4, kg = kg4 * 4;

    // ---- weight preload: 16 named frags (16 rows x K-half) ----
    u32x4 wh0, wh1, wh2, wh3, wh4, wh5, wh6, wh7;
    u32x4 wl0, wl1, wl2, wl3, wl4, wl5, wl6, wl7;
    int frow = rank * 64 + (w & 3) * 16 + (l & 15);
    {
        size_t fo = (((size_t)frow * 16 + kh * 8) * 4 + kg4) * 8;
        LD8W(Whi + fo, wh0, wh1, wh2, wh3, wh4, wh5, wh6, wh7);
        LD8W(Wlo + fo, wl0, wl1, wl2, wl3, wl4, wl5, wl6, wl7);
        asm volatile("s_waitcnt vmcnt(0)" ::: "memory");
    }

    int bX = ((l & 15) & 7) << 2;          // read-side per-batch XOR
    int bloc = 2 * w + (l >> 5);           // staged local batch (0..15)
    unsigned int sX = (unsigned int)((bloc & 7) << 2);  // write-side XOR
    int lam = l & 31;
    size_t soff = (size_t)(g * 16 + bloc) * 1024 + (size_t)lam * 4;

    u32x4 e0, e1, e2, e3, e4, e5, e6, e7;
    // ---- prologue: pre-issue round-0 for t=1 (buffer 0) ----
    ISSUE_STATE(sbuf + soff);

#pragma unroll 1
    for (int t = 1; t <= 1024; ++t) {
        // ---- prefetch pre-values for the 2 batches this wave finishes ----
        float pxw0, pxw1;
        {
            int r0 = 2 * kh;
            int bG0 = g * 16 + 4 * (l >> 4) + r0;
            pxw0 = out[(((size_t)bG0 << 10) + (t - 1)) * 512 + frow];
            pxw1 = out[(((size_t)(bG0 + 1) << 10) + (t - 1)) * 512 + frow];
        }

        // ---- check pre-issued round-0; retry until own slice tagged t-1 ----
        const unsigned int* pL = sbuf + (size_t)((t - 1) & 1) * TSTATE_U32 + soff;
        unsigned int exp = (unsigned int)(t - 1);
        VM0_FENCE();
        unsigned int bad = TAGBAD(exp);
        int rounds = 0;
        while (!__all(bad == 0)) {
            if (++rounds > 200000) break;  // terminate-not-hang safety net
            ISSUE_STATE(pL);
            VM0_FENCE();
            bad = TAGBAD(exp);
        }

        // ---- scatter into swizzled LDS tile ----
        {
            unsigned int* row = sval + bloc * 512;
            int kb = 2 * lam;
            *(u32x2*)&row[(kb)       ^ sX] = (u32x2){e0[0], e0[2]};
            *(u32x2*)&row[(kb + 64)  ^ sX] = (u32x2){e1[0], e1[2]};
            *(u32x2*)&row[(kb + 128) ^ sX] = (u32x2){e2[0], e2[2]};
            *(u32x2*)&row[(kb + 192) ^ sX] = (u32x2){e3[0], e3[2]};
            *(u32x2*)&row[(kb + 256) ^ sX] = (u32x2){e4[0], e4[2]};
            *(u32x2*)&row[(kb + 320) ^ sX] = (u32x2){e5[0], e5[2]};
            *(u32x2*)&row[(kb + 384) ^ sX] = (u32x2){e6[0], e6[2]};
            *(u32x2*)&row[(kb + 448) ^ sX] = (u32x2){e7[0], e7[2]};
        }
        __syncthreads();  // BAR-A: staging complete

        // ---- frag reads from LDS + 24 MFMAs ----
        const unsigned int* brow = sval + (l & 15) * 512;
        f32x4 acc = (f32x4)0.f;
#define RSTEP(KT, BH, BL)                                                         \
        {                                                                         \
            int k0 = kbase + (KT) * 32 + kg;                                      \
            u32x4 qa = *(const u32x4*)&brow[k0 ^ bX];                             \
            u32x4 qb = *(const u32x4*)&brow[(k0 + 16) ^ bX];                      \
            half8 Ah, Al;                                                         \
            unpack8(qa, qb, Ah, Al);                                              \
            acc = MFMA16(Ah, BC8(BH), acc);                                       \
            acc = MFMA16(Al, BC8(BH), acc);                                       \
            acc = MFMA16(Ah, BC8(BL), acc);                                       \
        }
        RSTEP(0, wh0, wl0);
        RSTEP(1, wh1, wl1);
        RSTEP(2, wh2, wl2);
        RSTEP(3, wh3, wl3);
        RSTEP(4, wh4, wl4);
        RSTEP(5, wh5, wl5);
        RSTEP(6, wh6, wl6);
        RSTEP(7, wh7, wl7);
#undef RSTEP

        // ---- pair exchange across K-halves (full acc) ----
        pex[w][l] = acc;
        __syncthreads();  // BAR-B
        f32x4 sum = acc + pex[w ^ 4][l];

        // ---- finish: this wave stores batches r = 2kh, 2kh+1 ----
        float s0 = kh ? sum[2] : sum[0];
        float s1 = kh ? sum[3] : sum[1];
        unsigned int* wbuf = sbuf + (size_t)(t & 1) * TSTATE_U32;
        int bG0 = g * 16 + 4 * (l >> 4) + 2 * kh;
        float v0 = s0 + pxw0;
        v0 = (v0 >= 0.f) ? v0 : 0.2f * v0;
        float v1 = s1 + pxw1;
        v1 = (v1 >= 0.f) ? v1 : 0.2f * v1;
        {
            _Float16 hi0 = (_Float16)v0, lo0 = (_Float16)(v0 - (float)hi0);
            _Float16 hi1 = (_Float16)v1, lo1 = (_Float16)(v1 - (float)hi1);
            unsigned int p0 = (unsigned int)__builtin_bit_cast(unsigned short, hi0) |
                              ((unsigned int)__builtin_bit_cast(unsigned short, lo0) << 16);
            unsigned int p1 = (unsigned int)__builtin_bit_cast(unsigned short, hi1) |
                              ((unsigned int)__builtin_bit_cast(unsigned short, lo1) << 16);
            unsigned long long t64 = (unsigned long long)(unsigned int)t << 32;
            ASTORE64(wbuf + ((size_t)bG0 * 512 + frow) * 2, (unsigned long long)p0 | t64);
            ASTORE64(wbuf + ((size_t)(bG0 + 1) * 512 + frow) * 2,
                     (unsigned long long)p1 | t64);
        }
        // ---- pre-issue round-0 for step t+1 (overlaps out stores / loopback)
        ISSUE_STATE(sbuf + (size_t)(t & 1) * TSTATE_U32 + soff);
        // ---- out stores fully off the critical path ----
        out[(((size_t)bG0 << 10) + (t - 1)) * 512 + frow] = v0;
        out[(((size_t)(bG0 + 1) << 10) + (t - 1)) * 512 + frow] = v1;
    }
}

// ---------------------------------------------------------------------------
extern "C" void kernel_launch(void* const* d_in, const int* in_sizes, int n_in,
                              void* d_out, int out_size, void* d_ws, size_t ws_size,
                              hipStream_t stream) {
    const float* x   = (const float*)d_in[0];
    const float* A   = (const float*)d_in[1];
    const float* Bv  = (const float*)d_in[2];
    const float* W_x = (const float*)d_in[3];
    const float* e_x = (const float*)d_in[4];
    const float* W_h = (const float*)d_in[5];
    const float* W_m = (const float*)d_in[6];
    float* out = (float*)d_out;

    char* ws = (char*)d_ws;
    size_t off = 0;
    auto carve = [&](size_t n) -> char* {
        char* p = ws + off;
        off += (n + 255) & ~(size_t)255;
        return p;
    };
    _Float16* Whi   = (_Float16*)carve(512 * 512 * 2);
    _Float16* Wlo   = (_Float16*)carve(512 * 512 * 2);
    _Float16* WxThi = (_Float16*)carve(512 * 128 * 2);
    _Float16* WxTlo = (_Float16*)carve(512 * 128 * 2);
    float* AT       = (float*)carve(256 * 256 * 4);
    float* u        = (float*)carve(64 * 1024 * 4);
    unsigned int* sbuf = (unsigned int*)carve((size_t)2 * TSTATE_U32 * 4);  // 512KB
    float* P2   = (float*)carve(256 * 256 * 4);
    float* P4   = (float*)carve(256 * 256 * 4);
    float* P8   = (float*)carve(256 * 256 * 4);
    float* P16  = (float*)carve(256 * 256 * 4);
    float* P32  = (float*)carve(256 * 256 * 4);
    float* P64  = (float*)carve(256 * 256 * 4);
    float* P2T  = (float*)carve(256 * 256 * 4);
    float* P4T  = (float*)carve(256 * 256 * 4);
    float* P8T  = (float*)carve(256 * 256 * 4);
    float* P16T = (float*)carve(256 * 256 * 4);
    float* P32T = (float*)carve(256 * 256 * 4);
    float* A64T = (float*)carve(256 * 256 * 4);
    float* V        = (float*)carve(1024 * 256 * 4);
    _Float16* CThi  = (_Float16*)carve(512 * 1024 * 2);

    // zero tagged state ping-pong buffers (tags=0 == expected for t=1)
    hipMemsetAsync(sbuf, 0, (size_t)2 * TSTATE_U32 * 4, stream);

    hipLaunchKernelGGL(k_prep, dim3(1281), dim3(256), 0, stream, A, Bv, W_x, W_h,
                       Whi, Wlo, WxThi, WxTlo, AT, V);
    hipLaunchKernelGGL(k_u, dim3(256, 64), dim3(256), 0, stream, x, e_x, u);

    // power chain: A^2..A^64 with transposes
    hipLaunchKernelGGL(k_a64, dim3(256), dim3(256), 0, stream, A, P2, P2T);
    hipLaunchKernelGGL(k_a64, dim3(256), dim3(256), 0, stream, P2, P4, P4T);
    hipLaunchKernelGGL(k_a64, dim3(256), dim3(256), 0, stream, P4, P8, P8T);
    hipLaunchKernelGGL(k_a64, dim3(256), dim3(256), 0, stream, P8, P16, P16T);
    hipLaunchKernelGGL(k_a64, dim3(256), dim3(256), 0, stream, P16, P32, P32T);
    hipLaunchKernelGGL(k_a64, dim3(256), dim3(256), 0, stream, P32, P64, A64T);

    // V[0..63] by doubling, then V[64..1023] by per-j chains
    hipLaunchKernelGGL(k_vdouble, dim3(1), dim3(256), 0, stream, AT, V, 1);
    hipLaunchKernelGGL(k_vdouble, dim3(2), dim3(256), 0, stream, P2T, V, 2);
    hipLaunchKernelGGL(k_vdouble, dim3(4), dim3(256), 0, stream, P4T, V, 4);
    hipLaunchKernelGGL(k_vdouble, dim3(8), dim3(256), 0, stream, P8T, V, 8);
    hipLaunchKernelGGL(k_vdouble, dim3(16), dim3(256), 0, stream, P16T, V, 16);
    hipLaunchKernelGGL(k_vdouble, dim3(32), dim3(256), 0, stream, P32T, V, 32);
    hipLaunchKernelGGL(k_vchain, dim3(64), dim3(256), 0, stream, A64T, V);
    hipLaunchKernelGGL(k_c, dim3(64), dim3(256), 0, stream, V, W_m, CThi);

    hipLaunchKernelGGL(k_preconv, dim3(1024, 2), dim3(256), 0, stream, x, u,
                       WxThi, WxTlo, CThi, out);

    void* args[] = {(void*)&Whi, (void*)&Wlo, (void*)&sbuf, (void*)&out};
    hipLaunchCooperativeKernel((void*)k_seq, dim3(32), dim3(512), args, 0, stream);
}